// Round 1
// baseline (8372.089 us; speedup 1.0000x reference)
//
#include <hip/hip_runtime.h>
#include <hip/hip_bf16.h>
#include <math.h>

#define NRR 175
#define KK 250
#define NN (NRR*KK)

#define S0_0 56
#define S0_1 350
#define S0_2 512
#define S1_0 28
#define S1_1 175
#define S1_2 256
#define S2_0 14
#define S2_1 88
#define S2_2 128
#define CAP1 350000
#define CAP2 69000
#define C1 32
#define C2 128

#define CELLS1 (S1_0*S1_1*S1_2)   // 1254400
#define CELLS2 (S2_0*S2_1*S2_2)   // 157696

#define ATT_SCALE 0.17677669529663687f

// ---------- helpers ----------
__device__ __forceinline__ int block_incl_scan(int v, int* s) {
    int t = threadIdx.x;
    s[t] = v; __syncthreads();
    #pragma unroll
    for (int d = 1; d < 256; d <<= 1) {
        int x = (t >= d) ? s[t - d] : 0;
        __syncthreads();
        s[t] += x;
        __syncthreads();
    }
    return s[t];
}

// candidate output coords o with 2o+off-1 == p, off in {0,1,2}, 0<=o<So
__device__ __forceinline__ void cand(int p, int So, int* o, int& no) {
    no = 0;
    if ((p & 1) == 0) {
        int q = p >> 1; if (q < So) o[no++] = q;
    } else {
        int q = (p - 1) >> 1; if (q < So) o[no++] = q;
        q = (p + 1) >> 1;     if (q < So) o[no++] = q;
    }
}

// ---------- stage kernels ----------
__global__ __launch_bounds__(256) void k_init(const float* __restrict__ vf,
                                              const int* __restrict__ coors,
                                              float* __restrict__ x,
                                              int* __restrict__ lut0,
                                              int* __restrict__ om1) {
    int i = blockIdx.x * 256 + threadIdx.x;
    if (i >= NN) return;
    x[i] = log10f(vf[i * 2]);
    int c1 = coors[i * 4 + 1], c2 = coors[i * 4 + 2], c3 = coors[i * 4 + 3];
    int e = 2 * c1 - 9, rg = 2 * c2, az = 2 * c3 + 149;
    atomicMax(&lut0[(e * S0_1 + rg) * S0_2 + az], i);
    int A[2], B[2], C[2]; int na, nb, nc;
    cand(e, S1_0, A, na); cand(rg, S1_1, B, nb); cand(az, S1_2, C, nc);
    for (int ia = 0; ia < na; ia++)
        for (int ib = 0; ib < nb; ib++)
            for (int ic = 0; ic < nc; ic++)
                om1[(A[ia] * S1_1 + B[ib]) * S1_2 + C[ic]] = 1;
}

__global__ __launch_bounds__(256) void k_attn(float* __restrict__ x_io,
    const int* __restrict__ coors,
    const float* __restrict__ et, const float* __restrict__ at,
    const float* __restrict__ wq, const float* __restrict__ bq,
    const float* __restrict__ wk, const float* __restrict__ bk,
    const float* __restrict__ wv, const float* __restrict__ bv) {
    __shared__ alignas(16) float xin[KK * 7];
    __shared__ alignas(16) float ksh[KK * 32];
    __shared__ float vsh[KK];
    __shared__ float xn[KK];
    const int r = blockIdx.x;
    const int t = threadIdx.x;
    for (int i = t; i < KK; i += 256) {
        int gi = r * KK + i;
        xin[i * 7 + 0] = x_io[gi];
        int c1 = coors[gi * 4 + 1], c3 = coors[gi * 4 + 3];
        xin[i * 7 + 1] = et[c1 * 3 + 0]; xin[i * 7 + 2] = et[c1 * 3 + 1]; xin[i * 7 + 3] = et[c1 * 3 + 2];
        xin[i * 7 + 4] = at[c3 * 3 + 0]; xin[i * 7 + 5] = at[c3 * 3 + 1]; xin[i * 7 + 6] = at[c3 * 3 + 2];
    }
    __syncthreads();
    for (int l = 0; l < 4; l++) {
        const float* wql = wq + l * 7 * 32; const float* bql = bq + l * 32;
        const float* wkl = wk + l * 7 * 32; const float* bkl = bk + l * 32;
        const float* wvl = wv + l * 7;      const float  bvl = bv[l];
        float q[32];
        if (t < KK) {
            float xi[7];
            #pragma unroll
            for (int ci = 0; ci < 7; ci++) xi[ci] = xin[t * 7 + ci];
            #pragma unroll
            for (int d = 0; d < 32; d++) {
                float aq = bql[d], ak = bkl[d];
                #pragma unroll
                for (int ci = 0; ci < 7; ci++) { aq += xi[ci] * wql[ci * 32 + d]; ak += xi[ci] * wkl[ci * 32 + d]; }
                q[d] = aq; ksh[t * 32 + d] = ak;
            }
            float av = bvl;
            #pragma unroll
            for (int ci = 0; ci < 7; ci++) av += xi[ci] * wvl[ci];
            vsh[t] = av;
        }
        __syncthreads();
        if (t < KK) {
            const float4* k4 = reinterpret_cast<const float4*>(ksh);
            float m = -1e30f;
            for (int j = 0; j < KK; j++) {
                float s = 0.f;
                #pragma unroll
                for (int d4 = 0; d4 < 8; d4++) {
                    float4 kv = k4[j * 8 + d4];
                    s += q[4*d4] * kv.x + q[4*d4+1] * kv.y + q[4*d4+2] * kv.z + q[4*d4+3] * kv.w;
                }
                m = fmaxf(m, s * ATT_SCALE);
            }
            float den = 0.f, num = 0.f;
            for (int j = 0; j < KK; j++) {
                float s = 0.f;
                #pragma unroll
                for (int d4 = 0; d4 < 8; d4++) {
                    float4 kv = k4[j * 8 + d4];
                    s += q[4*d4] * kv.x + q[4*d4+1] * kv.y + q[4*d4+2] * kv.z + q[4*d4+3] * kv.w;
                }
                float e = __expf(s * ATT_SCALE - m);
                den += e; num += e * vsh[j];
            }
            xn[t] = num / den;
        }
        __syncthreads();
        if (t < KK) xin[t * 7 + 0] = xn[t];
        __syncthreads();
    }
    if (t < KK) x_io[r * KK + t] = xin[t * 7 + 0];
}

__global__ __launch_bounds__(256) void k_f0(const int* __restrict__ coors,
    const float* __restrict__ x,
    const float* __restrict__ w_in, const float* __restrict__ b_in,
    const float* __restrict__ gg, const float* __restrict__ gb,
    float* __restrict__ f0) {
    int i = blockIdx.x * 256 + threadIdx.x;
    if (i >= NN) return;
    int c1 = coors[i * 4 + 1], c2 = coors[i * 4 + 2], c3 = coors[i * 4 + 3];
    float fe0 = (float)(2 * c1 - 9), fe1 = (float)(2 * c2), fe2 = (float)(2 * c3 + 149), fe3 = x[i];
    float tv[16];
    #pragma unroll
    for (int c = 0; c < 16; c++)
        tv[c] = b_in[c] + fe0 * w_in[c] + fe1 * w_in[16 + c] + fe2 * w_in[32 + c] + fe3 * w_in[48 + c];
    #pragma unroll
    for (int g = 0; g < 8; g++) {
        float a = tv[2 * g], b = tv[2 * g + 1];
        float m = 0.5f * (a + b);
        float va = 0.5f * ((a - m) * (a - m) + (b - m) * (b - m));
        float inv = rsqrtf(va + 1e-5f);
        f0[i * 16 + 2 * g]     = fmaxf((a - m) * inv * gg[2 * g]     + gb[2 * g],     0.f);
        f0[i * 16 + 2 * g + 1] = fmaxf((b - m) * inv * gg[2 * g + 1] + gb[2 * g + 1], 0.f);
    }
}

__global__ __launch_bounds__(256) void k_blocksum(const int* __restrict__ om,
                                                  int* __restrict__ partials, int ncells) {
    __shared__ int sh[256];
    int t = threadIdx.x;
    int base = blockIdx.x * 1024 + t * 4;
    int s = 0;
    #pragma unroll
    for (int q = 0; q < 4; q++) s += (base + q < ncells) ? om[base + q] : 0;
    int incl = block_incl_scan(s, sh);
    if (t == 255) partials[blockIdx.x] = incl;
}

__global__ __launch_bounds__(256) void k_scanparts(int* __restrict__ partials, int nparts,
                                                   int* __restrict__ pcnt, int cap) {
    __shared__ int sh[256];
    __shared__ int tot;
    int t = threadIdx.x;
    int chunk = (nparts + 255) / 256;
    int beg = t * chunk;
    int vals[8];
    int s = 0;
    #pragma unroll
    for (int i = 0; i < 8; i++) {
        if (i < chunk) {
            int ix = beg + i;
            int x = (ix < nparts) ? partials[ix] : 0;
            vals[i] = x; s += x;
        }
    }
    int incl = block_incl_scan(s, sh);
    int excl = incl - s;
    if (t == 255) tot = incl;
    int run = excl;
    #pragma unroll
    for (int i = 0; i < 8; i++) {
        if (i < chunk) {
            int ix = beg + i;
            if (ix < nparts) { partials[ix] = run; run += vals[i]; }
        }
    }
    __syncthreads();
    if (t == 0) *pcnt = min(tot, cap);
}

__global__ __launch_bounds__(256) void k_emit(const int* __restrict__ om,
                                              const int* __restrict__ partials,
                                              int* __restrict__ oc,
                                              int ncells, int D1, int D2, int cap) {
    __shared__ int sh[256];
    int t = threadIdx.x;
    int base = blockIdx.x * 1024 + t * 4;
    int v[4]; int s = 0;
    #pragma unroll
    for (int q = 0; q < 4; q++) { v[q] = (base + q < ncells) ? om[base + q] : 0; s += v[q]; }
    int incl = block_incl_scan(s, sh);
    int run = partials[blockIdx.x] + (incl - s);
    int D12 = D1 * D2;
    #pragma unroll
    for (int q = 0; q < 4; q++) {
        if (v[q]) {
            if (run < cap) {
                int lin = base + q;
                int i0 = lin / D12;
                int r2 = lin - i0 * D12;
                int i1 = r2 / D2;
                int i2 = r2 - i1 * D2;
                oc[run * 3] = i0; oc[run * 3 + 1] = i1; oc[run * 3 + 2] = i2;
            }
            run++;
        }
    }
}

__global__ __launch_bounds__(256) void k_lutscatter(const int* __restrict__ oc,
                                                    const int* __restrict__ pc,
                                                    int* __restrict__ lut, int D1, int D2) {
    int j = blockIdx.x * 256 + threadIdx.x;
    if (j >= *pc) return;
    lut[(oc[j * 3] * D1 + oc[j * 3 + 1]) * D2 + oc[j * 3 + 2]] = j;
}

__global__ __launch_bounds__(256) void k_mask2(const int* __restrict__ oc,
                                               const int* __restrict__ pc,
                                               int* __restrict__ om) {
    int j = blockIdx.x * 256 + threadIdx.x;
    if (j >= *pc) return;
    int p0 = oc[j * 3], p1 = oc[j * 3 + 1], p2 = oc[j * 3 + 2];
    int A[2], B[2], C[2]; int na, nb, nc;
    cand(p0, S2_0, A, na); cand(p1, S2_1, B, nb); cand(p2, S2_2, C, nc);
    for (int ia = 0; ia < na; ia++)
        for (int ib = 0; ib < nb; ib++)
            for (int ic = 0; ic < nc; ic++)
                om[(A[ia] * S2_1 + B[ib]) * S2_2 + C[ic]] = 1;
}

// ---------- generic gather-conv ----------
// MODE 0: bn + relu   MODE 1: bn + residual + relu   MODE 2: +bias, gn16, relu, scatter to output
template<int CIN, int COUT, int G, int R, int SD0, int SD1, int SD2, bool DOWN, int MODE>
__global__ __launch_bounds__(G * COUT)
void k_conv(const float* __restrict__ fin, const int* __restrict__ lut,
            const int* __restrict__ oc, const int* __restrict__ pc,
            const float* __restrict__ w, const float* __restrict__ p0,
            const float* __restrict__ p1, const float* __restrict__ p2,
            const float* __restrict__ res, float* __restrict__ fout) {
    constexpr int NTH = G * COUT;
    constexpr int RT = R / G;
    __shared__ alignas(16) float sf[R * CIN];
    __shared__ int sidx[R];
    __shared__ int sc[R * 3];
    const int n = *pc;
    const int j0 = blockIdx.x * R;
    if (j0 >= n) return;
    const int t = threadIdx.x;
    const int c = t % COUT;
    const int rg = t / COUT;
    float4* sf4 = reinterpret_cast<float4*>(sf);
    const float4* fin4 = reinterpret_cast<const float4*>(fin);

    for (int i = t; i < R * 3; i += NTH) {
        int j = j0 + i / 3;
        sc[i] = (j < n) ? oc[j * 3 + (i % 3)] : -1000000;
    }
    __syncthreads();

    float acc[RT];
    #pragma unroll
    for (int r = 0; r < RT; r++) acc[r] = 0.f;

    for (int k = 0; k < 27; k++) {
        const int dx = k / 9 - 1, dy = (k / 3) % 3 - 1, dz = k % 3 - 1;
        if (t < R) {
            int x = sc[t * 3], y = sc[t * 3 + 1], z = sc[t * 3 + 2];
            if (DOWN) { x = 2 * x + dx; y = 2 * y + dy; z = 2 * z + dz; }
            else      { x += dx; y += dy; z += dz; }
            int idx = -1;
            if ((unsigned)x < (unsigned)SD0 && (unsigned)y < (unsigned)SD1 && (unsigned)z < (unsigned)SD2)
                idx = lut[(x * SD1 + y) * SD2 + z];
            sidx[t] = idx;
        }
        __syncthreads();
        for (int i4 = t; i4 < R * (CIN / 4); i4 += NTH) {
            int r = i4 / (CIN / 4);
            int ci4 = i4 - r * (CIN / 4);
            int idx = sidx[r];
            float4 v;
            if (idx >= 0) v = fin4[(size_t)idx * (CIN / 4) + ci4];
            else          v = make_float4(0.f, 0.f, 0.f, 0.f);
            sf4[i4] = v;
        }
        __syncthreads();
        const float* __restrict__ wk = w + (size_t)k * CIN * COUT + c;
        #pragma unroll 2
        for (int ci4 = 0; ci4 < CIN / 4; ci4++) {
            float w0 = wk[(size_t)(4 * ci4 + 0) * COUT];
            float w1 = wk[(size_t)(4 * ci4 + 1) * COUT];
            float w2 = wk[(size_t)(4 * ci4 + 2) * COUT];
            float w3 = wk[(size_t)(4 * ci4 + 3) * COUT];
            #pragma unroll
            for (int r = 0; r < RT; r++) {
                float4 f4 = sf4[(rg * RT + r) * (CIN / 4) + ci4];
                acc[r] += f4.x * w0 + f4.y * w1 + f4.z * w2 + f4.w * w3;
            }
        }
        __syncthreads();
    }

    if (MODE == 0 || MODE == 1) {
        float g_ = p0[c], b_ = p0[COUT + c];
        float m_ = p0[2 * COUT + c];
        float iv = rsqrtf(p0[3 * COUT + c] + 1e-3f);
        #pragma unroll
        for (int r = 0; r < RT; r++) {
            int j = j0 + rg * RT + r;
            if (j >= n) continue;
            float y = (acc[r] - m_) * iv * g_ + b_;
            if (MODE == 1) y += res[(size_t)j * COUT + c];
            fout[(size_t)j * COUT + c] = fmaxf(y, 0.f);
        }
    } else {
        // MODE 2: G==1, COUT==128. bias + GN(16 groups of 8) + relu + scatter-transpose
        #pragma unroll
        for (int r = 0; r < RT; r++) {
            int j = j0 + r;
            float y = acc[r] + p0[c];
            float sum = y;
            sum += __shfl_xor(sum, 1, 8);
            sum += __shfl_xor(sum, 2, 8);
            sum += __shfl_xor(sum, 4, 8);
            float m = sum * 0.125f;
            float d = y - m;
            float q = d * d;
            q += __shfl_xor(q, 1, 8);
            q += __shfl_xor(q, 2, 8);
            q += __shfl_xor(q, 4, 8);
            float var = q * 0.125f;
            float o = d * rsqrtf(var + 1e-5f) * p1[c] + p2[c];
            o = fmaxf(o, 0.f);
            if (j < n) {
                int aa = oc[j * 3], bb = oc[j * 3 + 1], cc = oc[j * 3 + 2];
                fout[(((size_t)c * S2_2 + cc) * S2_1 + bb) * S2_0 + aa] = o;
            }
        }
    }
}

// ---------- host ----------
extern "C" void kernel_launch(void* const* d_in, const int* in_sizes, int n_in,
                              void* d_out, int out_size, void* d_ws, size_t ws_size,
                              hipStream_t stream) {
    const float* vf    = (const float*)d_in[0];
    const int*   coors = (const int*)d_in[1];
    const float* et    = (const float*)d_in[3];
    const float* at    = (const float*)d_in[4];
    const float* wq    = (const float*)d_in[5];
    const float* bq    = (const float*)d_in[6];
    const float* wk_   = (const float*)d_in[7];
    const float* bk    = (const float*)d_in[8];
    const float* wv    = (const float*)d_in[9];
    const float* bv    = (const float*)d_in[10];
    const float* w_in  = (const float*)d_in[11];
    const float* b_in  = (const float*)d_in[12];
    const float* gin_g = (const float*)d_in[13];
    const float* gin_b = (const float*)d_in[14];
    const float* w_d1  = (const float*)d_in[15];
    const float* bn_d1 = (const float*)d_in[16];
    const float* w_r1  = (const float*)d_in[17];
    const float* bn_r1 = (const float*)d_in[18];
    const float* w_d2  = (const float*)d_in[19];
    const float* bn_d2 = (const float*)d_in[20];
    const float* w_r2  = (const float*)d_in[21];
    const float* bn_r2 = (const float*)d_in[22];
    const float* w_out = (const float*)d_in[23];
    const float* b_out = (const float*)d_in[24];
    const float* gout_g= (const float*)d_in[25];
    const float* gout_b= (const float*)d_in[26];

    char* ws = (char*)d_ws;
    size_t cur = 0;
    auto take = [&](size_t bytes) -> char* {
        char* p = ws + cur;
        cur += (bytes + 255) & ~(size_t)255;
        return p;
    };
    // Aliased region U:
    //  phase 1: x_att @0 (175 KB), f0 @262144 (2.8 MB), lut0 @4194304 (40.1 MB)
    //  phase 2: fB1 @0 (44.8 MB)
    //  phase 3: fA2 @0 (35.3 MB), fB2 @35328256 (35.3 MB)
    char* U = take(70656512);
    float* x_att = (float*)U;
    float* f0    = (float*)(U + 262144);
    int*   lut0  = (int*)(U + 4194304);
    float* fB1   = (float*)U;
    float* fA2   = (float*)U;
    float* fB2   = (float*)(U + 35328256);

    int*   om1      = (int*)take((size_t)CELLS1 * 4);
    int*   om2      = (int*)take((size_t)CELLS2 * 4);
    int*   partials = (int*)take(8192);
    int*   cnt      = (int*)take(256);
    int*   oc1      = (int*)take((size_t)CAP1 * 3 * 4);
    int*   oc2      = (int*)take((size_t)CAP2 * 3 * 4);
    float* fA1      = (float*)take((size_t)CAP1 * C1 * 4);
    int*   lut1     = (int*)take((size_t)CELLS1 * 4);
    int*   lut2     = (int*)take((size_t)CELLS2 * 4);

    // init
    hipMemsetAsync(d_out, 0, (size_t)out_size * 4, stream);
    hipMemsetAsync(lut0, 0xFF, (size_t)S0_0 * S0_1 * S0_2 * 4, stream);
    hipMemsetAsync(om1, 0, (size_t)CELLS1 * 4, stream);
    hipMemsetAsync(om2, 0, (size_t)CELLS2 * 4, stream);
    hipMemsetAsync(lut1, 0xFF, (size_t)CELLS1 * 4, stream);
    hipMemsetAsync(lut2, 0xFF, (size_t)CELLS2 * 4, stream);

    const int gN  = (NN + 255) / 256;
    const int gB1 = CELLS1 / 1024;        // 1225
    const int gB2 = CELLS2 / 1024;        // 154
    const int gC1 = (CAP1 + 31) / 32;     // 10938
    const int gC2 = (CAP2 + 15) / 16;     // 4313
    const int gS1 = (CAP1 + 255) / 256;
    const int gS2 = (CAP2 + 255) / 256;

    k_init<<<gN, 256, 0, stream>>>(vf, coors, x_att, lut0, om1);
    k_attn<<<NRR, 256, 0, stream>>>(x_att, coors, et, at, wq, bq, wk_, bk, wv, bv);
    k_f0<<<gN, 256, 0, stream>>>(coors, x_att, w_in, b_in, gin_g, gin_b, f0);

    // level-1 active set
    k_blocksum<<<gB1, 256, 0, stream>>>(om1, partials, CELLS1);
    k_scanparts<<<1, 256, 0, stream>>>(partials, gB1, cnt, CAP1);
    k_emit<<<gB1, 256, 0, stream>>>(om1, partials, oc1, CELLS1, S1_1, S1_2, CAP1);

    // down conv 1 (16 -> 32), bn + relu
    k_conv<16, C1, 8, 32, S0_0, S0_1, S0_2, true, 0><<<gC1, 256, 0, stream>>>(
        f0, lut0, oc1, cnt, w_d1, bn_d1, nullptr, nullptr, nullptr, fA1);
    k_lutscatter<<<gS1, 256, 0, stream>>>(oc1, cnt, lut1, S1_1, S1_2);

    const int wr1s = 27 * C1 * C1, bnr1s = 4 * C1;
    // resblock 1.0
    k_conv<C1, C1, 8, 32, S1_0, S1_1, S1_2, false, 0><<<gC1, 256, 0, stream>>>(
        fA1, lut1, oc1, cnt, w_r1 + 0 * wr1s, bn_r1 + 0 * bnr1s, nullptr, nullptr, nullptr, fB1);
    k_conv<C1, C1, 8, 32, S1_0, S1_1, S1_2, false, 1><<<gC1, 256, 0, stream>>>(
        fB1, lut1, oc1, cnt, w_r1 + 1 * wr1s, bn_r1 + 1 * bnr1s, nullptr, nullptr, fA1, fA1);
    // resblock 1.1
    k_conv<C1, C1, 8, 32, S1_0, S1_1, S1_2, false, 0><<<gC1, 256, 0, stream>>>(
        fA1, lut1, oc1, cnt, w_r1 + 2 * wr1s, bn_r1 + 2 * bnr1s, nullptr, nullptr, nullptr, fB1);
    k_conv<C1, C1, 8, 32, S1_0, S1_1, S1_2, false, 1><<<gC1, 256, 0, stream>>>(
        fB1, lut1, oc1, cnt, w_r1 + 3 * wr1s, bn_r1 + 3 * bnr1s, nullptr, nullptr, fA1, fA1);

    // level-2 active set
    k_mask2<<<gS1, 256, 0, stream>>>(oc1, cnt, om2);
    k_blocksum<<<gB2, 256, 0, stream>>>(om2, partials, CELLS2);
    k_scanparts<<<1, 256, 0, stream>>>(partials, gB2, cnt + 1, CAP2);
    k_emit<<<gB2, 256, 0, stream>>>(om2, partials, oc2, CELLS2, S2_1, S2_2, CAP2);

    // down conv 2 (32 -> 128), bn + relu
    k_conv<C1, C2, 1, 16, S1_0, S1_1, S1_2, true, 0><<<gC2, 128, 0, stream>>>(
        fA1, lut1, oc2, cnt + 1, w_d2, bn_d2, nullptr, nullptr, nullptr, fA2);
    k_lutscatter<<<gS2, 256, 0, stream>>>(oc2, cnt + 1, lut2, S2_1, S2_2);

    const int wr2s = 27 * C2 * C2, bnr2s = 4 * C2;
    // resblock 2.0
    k_conv<C2, C2, 1, 16, S2_0, S2_1, S2_2, false, 0><<<gC2, 128, 0, stream>>>(
        fA2, lut2, oc2, cnt + 1, w_r2 + 0 * (size_t)wr2s, bn_r2 + 0 * bnr2s, nullptr, nullptr, nullptr, fB2);
    k_conv<C2, C2, 1, 16, S2_0, S2_1, S2_2, false, 1><<<gC2, 128, 0, stream>>>(
        fB2, lut2, oc2, cnt + 1, w_r2 + 1 * (size_t)wr2s, bn_r2 + 1 * bnr2s, nullptr, nullptr, fA2, fA2);
    // resblock 2.1
    k_conv<C2, C2, 1, 16, S2_0, S2_1, S2_2, false, 0><<<gC2, 128, 0, stream>>>(
        fA2, lut2, oc2, cnt + 1, w_r2 + 2 * (size_t)wr2s, bn_r2 + 2 * bnr2s, nullptr, nullptr, nullptr, fB2);
    k_conv<C2, C2, 1, 16, S2_0, S2_1, S2_2, false, 1><<<gC2, 128, 0, stream>>>(
        fB2, lut2, oc2, cnt + 1, w_r2 + 3 * (size_t)wr2s, bn_r2 + 3 * bnr2s, nullptr, nullptr, fA2, fA2);

    // out conv + bias + gn16 + relu + scatter into transposed dense output
    k_conv<C2, C2, 1, 16, S2_0, S2_1, S2_2, false, 2><<<gC2, 128, 0, stream>>>(
        fA2, lut2, oc2, cnt + 1, w_out, b_out, gout_g, gout_b, nullptr, (float*)d_out);
}

// Round 2
// 1504.069 us; speedup vs baseline: 5.5663x; 5.5663x over previous
//
#include <hip/hip_runtime.h>
#include <math.h>

#define NRR 175
#define KK 250
#define NN (NRR*KK)

#define S0_0 56
#define S0_1 350
#define S0_2 512
#define S1_0 28
#define S1_1 175
#define S1_2 256
#define S2_0 14
#define S2_1 88
#define S2_2 128
#define CAP1 350000
#define CAP2 69000
#define C1 32
#define C2 128

#define CELLS0 (S0_0*S0_1*S0_2)   // 10035200
#define CELLS1 (S1_0*S1_1*S1_2)   // 1254400
#define CELLS2 (S2_0*S2_1*S2_2)   // 157696

#define ATT_SCALE 0.17677669529663687f

typedef __attribute__((ext_vector_type(8))) __bf16 bf16x8;
typedef __attribute__((ext_vector_type(16))) float f32x16;

// ---------- bf16 helpers (RNE) ----------
__device__ __forceinline__ unsigned short f2b(float x) {
    unsigned int u = __builtin_bit_cast(unsigned int, x);
    unsigned int r = u + 0x7FFFu + ((u >> 16) & 1u);
    return (unsigned short)(r >> 16);
}
__device__ __forceinline__ float b2f(unsigned short h) {
    return __builtin_bit_cast(float, (unsigned int)h << 16);
}

// ---------- helpers ----------
__device__ __forceinline__ int block_incl_scan(int v, int* s) {
    int t = threadIdx.x;
    s[t] = v; __syncthreads();
    #pragma unroll
    for (int d = 1; d < 256; d <<= 1) {
        int x = (t >= d) ? s[t - d] : 0;
        __syncthreads();
        s[t] += x;
        __syncthreads();
    }
    return s[t];
}

__device__ __forceinline__ void cand(int p, int So, int* o, int& no) {
    no = 0;
    if ((p & 1) == 0) {
        int q = p >> 1; if (q < So) o[no++] = q;
    } else {
        int q = (p - 1) >> 1; if (q < So) o[no++] = q;
        q = (p + 1) >> 1;     if (q < So) o[no++] = q;
    }
}

// ---------- stage kernels ----------
__global__ __launch_bounds__(256) void k_init(const float* __restrict__ vf,
                                              const int* __restrict__ coors,
                                              float* __restrict__ x,
                                              int* __restrict__ lut0,
                                              int* __restrict__ om1) {
    int i = blockIdx.x * 256 + threadIdx.x;
    if (i >= NN) return;
    x[i] = log10f(vf[i * 2]);
    int c1 = coors[i * 4 + 1], c2 = coors[i * 4 + 2], c3 = coors[i * 4 + 3];
    int e = 2 * c1 - 9, rg = 2 * c2, az = 2 * c3 + 149;
    atomicMax(&lut0[(e * S0_1 + rg) * S0_2 + az], i);
    int A[2], B[2], C[2]; int na, nb, nc;
    cand(e, S1_0, A, na); cand(rg, S1_1, B, nb); cand(az, S1_2, C, nc);
    for (int ia = 0; ia < na; ia++)
        for (int ib = 0; ib < nb; ib++)
            for (int ic = 0; ic < nc; ic++)
                om1[(A[ia] * S1_1 + B[ib]) * S1_2 + C[ic]] = 1;
}

__global__ __launch_bounds__(256) void k_attn(float* __restrict__ x_io,
    const int* __restrict__ coors,
    const float* __restrict__ et, const float* __restrict__ at,
    const float* __restrict__ wq, const float* __restrict__ bq,
    const float* __restrict__ wk, const float* __restrict__ bk,
    const float* __restrict__ wv, const float* __restrict__ bv) {
    __shared__ alignas(16) float xin[KK * 7];
    __shared__ alignas(16) float ksh[KK * 32];
    __shared__ float vsh[KK];
    __shared__ float xn[KK];
    const int r = blockIdx.x;
    const int t = threadIdx.x;
    for (int i = t; i < KK; i += 256) {
        int gi = r * KK + i;
        xin[i * 7 + 0] = x_io[gi];
        int c1 = coors[gi * 4 + 1], c3 = coors[gi * 4 + 3];
        xin[i * 7 + 1] = et[c1 * 3 + 0]; xin[i * 7 + 2] = et[c1 * 3 + 1]; xin[i * 7 + 3] = et[c1 * 3 + 2];
        xin[i * 7 + 4] = at[c3 * 3 + 0]; xin[i * 7 + 5] = at[c3 * 3 + 1]; xin[i * 7 + 6] = at[c3 * 3 + 2];
    }
    __syncthreads();
    for (int l = 0; l < 4; l++) {
        const float* wql = wq + l * 7 * 32; const float* bql = bq + l * 32;
        const float* wkl = wk + l * 7 * 32; const float* bkl = bk + l * 32;
        const float* wvl = wv + l * 7;      const float  bvl = bv[l];
        float q[32];
        if (t < KK) {
            float xi[7];
            #pragma unroll
            for (int ci = 0; ci < 7; ci++) xi[ci] = xin[t * 7 + ci];
            #pragma unroll
            for (int d = 0; d < 32; d++) {
                float aq = bql[d], ak = bkl[d];
                #pragma unroll
                for (int ci = 0; ci < 7; ci++) { aq += xi[ci] * wql[ci * 32 + d]; ak += xi[ci] * wkl[ci * 32 + d]; }
                q[d] = aq; ksh[t * 32 + d] = ak;
            }
            float av = bvl;
            #pragma unroll
            for (int ci = 0; ci < 7; ci++) av += xi[ci] * wvl[ci];
            vsh[t] = av;
        }
        __syncthreads();
        if (t < KK) {
            const float4* k4 = reinterpret_cast<const float4*>(ksh);
            float m = -1e30f;
            for (int j = 0; j < KK; j++) {
                float s = 0.f;
                #pragma unroll
                for (int d4 = 0; d4 < 8; d4++) {
                    float4 kv = k4[j * 8 + d4];
                    s += q[4*d4] * kv.x + q[4*d4+1] * kv.y + q[4*d4+2] * kv.z + q[4*d4+3] * kv.w;
                }
                m = fmaxf(m, s * ATT_SCALE);
            }
            float den = 0.f, num = 0.f;
            for (int j = 0; j < KK; j++) {
                float s = 0.f;
                #pragma unroll
                for (int d4 = 0; d4 < 8; d4++) {
                    float4 kv = k4[j * 8 + d4];
                    s += q[4*d4] * kv.x + q[4*d4+1] * kv.y + q[4*d4+2] * kv.z + q[4*d4+3] * kv.w;
                }
                float e = __expf(s * ATT_SCALE - m);
                den += e; num += e * vsh[j];
            }
            xn[t] = num / den;
        }
        __syncthreads();
        if (t < KK) xin[t * 7 + 0] = xn[t];
        __syncthreads();
    }
    if (t < KK) x_io[r * KK + t] = xin[t * 7 + 0];
}

__global__ __launch_bounds__(256) void k_f0(const int* __restrict__ coors,
    const float* __restrict__ x,
    const float* __restrict__ w_in, const float* __restrict__ b_in,
    const float* __restrict__ gg, const float* __restrict__ gb,
    unsigned short* __restrict__ f0) {
    int i = blockIdx.x * 256 + threadIdx.x;
    if (i >= NN) return;
    int c1 = coors[i * 4 + 1], c2 = coors[i * 4 + 2], c3 = coors[i * 4 + 3];
    float fe0 = (float)(2 * c1 - 9), fe1 = (float)(2 * c2), fe2 = (float)(2 * c3 + 149), fe3 = x[i];
    float tv[16];
    #pragma unroll
    for (int c = 0; c < 16; c++)
        tv[c] = b_in[c] + fe0 * w_in[c] + fe1 * w_in[16 + c] + fe2 * w_in[32 + c] + fe3 * w_in[48 + c];
    #pragma unroll
    for (int g = 0; g < 8; g++) {
        float a = tv[2 * g], b = tv[2 * g + 1];
        float m = 0.5f * (a + b);
        float va = 0.5f * ((a - m) * (a - m) + (b - m) * (b - m));
        float inv = rsqrtf(va + 1e-5f);
        f0[i * 16 + 2 * g]     = f2b(fmaxf((a - m) * inv * gg[2 * g]     + gb[2 * g],     0.f));
        f0[i * 16 + 2 * g + 1] = f2b(fmaxf((b - m) * inv * gg[2 * g + 1] + gb[2 * g + 1], 0.f));
    }
}

__global__ __launch_bounds__(256) void k_blocksum(const int* __restrict__ om,
                                                  int* __restrict__ partials, int ncells) {
    __shared__ int sh[256];
    int t = threadIdx.x;
    int base = blockIdx.x * 1024 + t * 4;
    int s = 0;
    #pragma unroll
    for (int q = 0; q < 4; q++) s += (base + q < ncells) ? om[base + q] : 0;
    int incl = block_incl_scan(s, sh);
    if (t == 255) partials[blockIdx.x] = incl;
}

__global__ __launch_bounds__(256) void k_scanparts(int* __restrict__ partials, int nparts,
                                                   int* __restrict__ pcnt, int cap) {
    __shared__ int sh[256];
    __shared__ int tot;
    int t = threadIdx.x;
    int chunk = (nparts + 255) / 256;
    int beg = t * chunk;
    int vals[8];
    int s = 0;
    #pragma unroll
    for (int i = 0; i < 8; i++) {
        if (i < chunk) {
            int ix = beg + i;
            int x = (ix < nparts) ? partials[ix] : 0;
            vals[i] = x; s += x;
        }
    }
    int incl = block_incl_scan(s, sh);
    int excl = incl - s;
    if (t == 255) tot = incl;
    int run = excl;
    #pragma unroll
    for (int i = 0; i < 8; i++) {
        if (i < chunk) {
            int ix = beg + i;
            if (ix < nparts) { partials[ix] = run; run += vals[i]; }
        }
    }
    __syncthreads();
    if (t == 0) *pcnt = min(tot, cap);
}

__global__ __launch_bounds__(256) void k_emit(const int* __restrict__ om,
                                              const int* __restrict__ partials,
                                              int* __restrict__ oc,
                                              int ncells, int D1, int D2, int cap) {
    __shared__ int sh[256];
    int t = threadIdx.x;
    int base = blockIdx.x * 1024 + t * 4;
    int v[4]; int s = 0;
    #pragma unroll
    for (int q = 0; q < 4; q++) { v[q] = (base + q < ncells) ? om[base + q] : 0; s += v[q]; }
    int incl = block_incl_scan(s, sh);
    int run = partials[blockIdx.x] + (incl - s);
    int D12 = D1 * D2;
    #pragma unroll
    for (int q = 0; q < 4; q++) {
        if (v[q]) {
            if (run < cap) {
                int lin = base + q;
                int i0 = lin / D12;
                int r2 = lin - i0 * D12;
                int i1 = r2 / D2;
                int i2 = r2 - i1 * D2;
                oc[run * 3] = i0; oc[run * 3 + 1] = i1; oc[run * 3 + 2] = i2;
            }
            run++;
        }
    }
}

__global__ __launch_bounds__(256) void k_lutscatter(const int* __restrict__ oc,
                                                    const int* __restrict__ pc,
                                                    int* __restrict__ lut, int D1, int D2) {
    int j = blockIdx.x * 256 + threadIdx.x;
    if (j >= *pc) return;
    lut[(oc[j * 3] * D1 + oc[j * 3 + 1]) * D2 + oc[j * 3 + 2]] = j;
}

__global__ __launch_bounds__(256) void k_mask2(const int* __restrict__ oc,
                                               const int* __restrict__ pc,
                                               int* __restrict__ om) {
    int j = blockIdx.x * 256 + threadIdx.x;
    if (j >= *pc) return;
    int p0 = oc[j * 3], p1 = oc[j * 3 + 1], p2 = oc[j * 3 + 2];
    int A[2], B[2], C[2]; int na, nb, nc;
    cand(p0, S2_0, A, na); cand(p1, S2_1, B, nb); cand(p2, S2_2, C, nc);
    for (int ia = 0; ia < na; ia++)
        for (int ib = 0; ib < nb; ib++)
            for (int ic = 0; ic < nc; ic++)
                om[(A[ia] * S2_1 + B[ib]) * S2_2 + C[ic]] = 1;
}

// ---------- weight pre-pack into MFMA B-fragment order ----------
// value = w[kk][ci][co] -> wp[(((kk*KS+ks)*NT+nt)*64+lane)*8+j]
// ci = ks*16 + (lane>>5)*8 + j ; co = nt*32 + (lane&31)
__global__ __launch_bounds__(256) void k_prepack(const float* __restrict__ w,
        unsigned short* __restrict__ wp, int nk, int cin, int cout) {
    int tid = blockIdx.x * 256 + threadIdx.x;
    int tot = nk * cin * cout;
    if (tid >= tot) return;
    int co = tid % cout; int rest = tid / cout; int ci = rest % cin; int kk = rest / cin;
    int ks = ci >> 4, kr = ci & 15, half = kr >> 3, j = kr & 7;
    int nt = co >> 5, cl = co & 31, lane = half * 32 + cl;
    wp[((((size_t)kk * (cin >> 4) + ks) * (cout >> 5) + nt) * 64 + lane) * 8 + j] = f2b(w[tid]);
}

// ---------- MFMA gather-conv ----------
// Block: 128 gathered rows x COUT channels, 256 threads (4 waves).
// COUT=128: wave tile 64x64 (2x2 of 32x32). COUT=32: wave tile 32x32 (4 waves stack M).
// A staged in LDS (bf16, row stride CIN+8 ushorts = uniform-bank layout);
// B read fragment-ordered from global (L1-resident, no LDS).
// MODE 0: bn+relu  MODE 1: bn+res+relu  MODE 2: bias+gn16+relu+transposed scatter (fp32 out)
template<int CIN, int COUT, int SD0, int SD1, int SD2, bool DOWN, int MODE>
__global__ __launch_bounds__(256, 2)
void k_mconv(const unsigned short* __restrict__ fin, const int* __restrict__ lut,
             const int* __restrict__ oc, const int* __restrict__ pc,
             const unsigned short* __restrict__ wp,
             const float* __restrict__ p0, const float* __restrict__ p1,
             const float* __restrict__ p2,
             const unsigned short* __restrict__ res, void* __restrict__ fout_) {
    constexpr int KS = CIN / 16;
    constexpr int NT = COUT / 32;
    constexpr int SROW = CIN + 8;
    constexpr int CPR = CIN / 8;       // 16B chunks per row
    constexpr int TM = (COUT == 128) ? 2 : 1;
    constexpr int TN = (COUT == 128) ? 2 : 1;
    __shared__ unsigned short sA[128 * SROW];
    __shared__ int sidx[128];
    __shared__ int sc[128 * 3];

    const int n = *pc;
    const int j0 = blockIdx.x * 128;
    if (j0 >= n) return;
    const int t = threadIdx.x;
    const int w = t >> 6;
    const int ln = t & 63;
    const int l31 = ln & 31;
    const int lh = ln >> 5;
    const int rowbase = (COUT == 128) ? (w & 1) * 64 : w * 32;
    const int colt0  = (COUT == 128) ? (w >> 1) * TN : 0;

    for (int i = t; i < 128 * 3; i += 256) {
        int j = j0 + i / 3;
        sc[i] = (j < n) ? oc[j * 3 + (i % 3)] : -1000000;
    }
    __syncthreads();

    f32x16 acc[TM][TN];
    #pragma unroll
    for (int a = 0; a < TM; a++)
        #pragma unroll
        for (int b = 0; b < TN; b++)
            #pragma unroll
            for (int q = 0; q < 16; q++) acc[a][b][q] = 0.f;

    for (int k = 0; k < 27; k++) {
        const int dx = k / 9 - 1, dy = (k / 3) % 3 - 1, dz = k % 3 - 1;
        if (t < 128) {
            int x = sc[t * 3], y = sc[t * 3 + 1], z = sc[t * 3 + 2];
            if (DOWN) { x = 2 * x + dx; y = 2 * y + dy; z = 2 * z + dz; }
            else      { x += dx; y += dy; z += dz; }
            int idx = -1;
            if ((unsigned)x < (unsigned)SD0 && (unsigned)y < (unsigned)SD1 && (unsigned)z < (unsigned)SD2)
                idx = lut[(x * SD1 + y) * SD2 + z];
            sidx[t] = idx;
        }
        __syncthreads();
        #pragma unroll
        for (int it = 0; it < (128 * CPR) / 256; it++) {
            int cc = t + it * 256;
            int r = cc / CPR, c = cc % CPR;
            int idx = sidx[r];
            uint4 v = make_uint4(0, 0, 0, 0);
            if (idx >= 0) v = *(const uint4*)(fin + (size_t)idx * CIN + c * 8);
            *(uint4*)(&sA[r * SROW + c * 8]) = v;
        }
        __syncthreads();
        const unsigned short* wk = wp + (size_t)k * KS * NT * 512;
        #pragma unroll
        for (int ks = 0; ks < KS; ks++) {
            bf16x8 afr[TM], bfr[TN];
            #pragma unroll
            for (int a = 0; a < TM; a++)
                afr[a] = *(const bf16x8*)(&sA[(rowbase + a * 32 + l31) * SROW + ks * 16 + lh * 8]);
            #pragma unroll
            for (int b = 0; b < TN; b++)
                bfr[b] = *(const bf16x8*)(wk + ((size_t)(ks * NT + colt0 + b) * 64 + ln) * 8);
            #pragma unroll
            for (int a = 0; a < TM; a++)
                #pragma unroll
                for (int b = 0; b < TN; b++)
                    acc[a][b] = __builtin_amdgcn_mfma_f32_32x32x16_bf16(afr[a], bfr[b], acc[a][b], 0, 0, 0);
        }
        __syncthreads();
    }

    if (MODE != 2) {
        unsigned short* fout = (unsigned short*)fout_;
        #pragma unroll
        for (int b = 0; b < TN; b++) {
            int co = (colt0 + b) * 32 + l31;
            float g_ = p0[co], bb_ = p0[COUT + co], m_ = p0[2 * COUT + co];
            float iv = rsqrtf(p0[3 * COUT + co] + 1e-3f);
            #pragma unroll
            for (int a = 0; a < TM; a++) {
                #pragma unroll
                for (int r = 0; r < 16; r++) {
                    int jr = rowbase + a * 32 + (r & 3) + 8 * (r >> 2) + 4 * lh;
                    int j = j0 + jr;
                    if (j < n) {
                        float y = (acc[a][b][r] - m_) * iv * g_ + bb_;
                        if (MODE == 1) y += b2f(res[(size_t)j * COUT + co]);
                        fout[(size_t)j * COUT + co] = f2b(fmaxf(y, 0.f));
                    }
                }
            }
        }
    } else {
        float* dout = (float*)fout_;
        #pragma unroll
        for (int b = 0; b < TN; b++) {
            int co = (colt0 + b) * 32 + l31;
            float bias = p0[co], gg_ = p1[co], gb_ = p2[co];
            #pragma unroll
            for (int a = 0; a < TM; a++) {
                #pragma unroll
                for (int r = 0; r < 16; r++) {
                    int jr = rowbase + a * 32 + (r & 3) + 8 * (r >> 2) + 4 * lh;
                    int j = j0 + jr;
                    float y = acc[a][b][r] + bias;
                    float s = y;
                    s += __shfl_xor(s, 1, 8);
                    s += __shfl_xor(s, 2, 8);
                    s += __shfl_xor(s, 4, 8);
                    float m = s * 0.125f;
                    float d = y - m;
                    float q2 = d * d;
                    q2 += __shfl_xor(q2, 1, 8);
                    q2 += __shfl_xor(q2, 2, 8);
                    q2 += __shfl_xor(q2, 4, 8);
                    float var = q2 * 0.125f;
                    float o = fmaxf(d * rsqrtf(var + 1e-5f) * gg_ + gb_, 0.f);
                    if (j < n) {
                        int aa = sc[jr * 3], bb = sc[jr * 3 + 1], cc = sc[jr * 3 + 2];
                        dout[(((size_t)co * S2_2 + cc) * S2_1 + bb) * S2_0 + aa] = o;
                    }
                }
            }
        }
    }
}

// ---------- host ----------
extern "C" void kernel_launch(void* const* d_in, const int* in_sizes, int n_in,
                              void* d_out, int out_size, void* d_ws, size_t ws_size,
                              hipStream_t stream) {
    const float* vf    = (const float*)d_in[0];
    const int*   coors = (const int*)d_in[1];
    const float* et    = (const float*)d_in[3];
    const float* at    = (const float*)d_in[4];
    const float* wq    = (const float*)d_in[5];
    const float* bq    = (const float*)d_in[6];
    const float* wk_   = (const float*)d_in[7];
    const float* bk    = (const float*)d_in[8];
    const float* wv    = (const float*)d_in[9];
    const float* bv    = (const float*)d_in[10];
    const float* w_in  = (const float*)d_in[11];
    const float* b_in  = (const float*)d_in[12];
    const float* gin_g = (const float*)d_in[13];
    const float* gin_b = (const float*)d_in[14];
    const float* w_d1  = (const float*)d_in[15];
    const float* bn_d1 = (const float*)d_in[16];
    const float* w_r1  = (const float*)d_in[17];
    const float* bn_r1 = (const float*)d_in[18];
    const float* w_d2  = (const float*)d_in[19];
    const float* bn_d2 = (const float*)d_in[20];
    const float* w_r2  = (const float*)d_in[21];
    const float* bn_r2 = (const float*)d_in[22];
    const float* w_out = (const float*)d_in[23];
    const float* b_out = (const float*)d_in[24];
    const float* gout_g= (const float*)d_in[25];
    const float* gout_b= (const float*)d_in[26];

    char* ws = (char*)d_ws;
    size_t cur = 0;
    auto take = [&](size_t bytes) -> char* {
        char* p = ws + cur;
        cur += (bytes + 255) & ~(size_t)255;
        return p;
    };
    // Aliased region U (44.4 MB):
    //  phase 1: x_att @0 (175 KB), f0 bf16 @262144 (1.4 MB), lut0 @4194304 (40.1 MB)
    //  phase 2: fB1 bf16 @0 (22.4 MB)   [after down1; lut0/f0 dead]
    //  phase 3: fA2 bf16 @0 (17.7 MB), fB2 bf16 @17694720 (17.7 MB) [after res1]
    char* U = take((size_t)4194304 + (size_t)CELLS0 * 4);
    float*          x_att = (float*)U;
    unsigned short* f0    = (unsigned short*)(U + 262144);
    int*            lut0  = (int*)(U + 4194304);
    unsigned short* fB1   = (unsigned short*)U;
    unsigned short* fA2   = (unsigned short*)U;
    unsigned short* fB2   = (unsigned short*)(U + 17694720);

    int*   om1      = (int*)take((size_t)CELLS1 * 4);
    int*   om2      = (int*)take((size_t)CELLS2 * 4);
    int*   partials = (int*)take(8192);
    int*   cnt      = (int*)take(256);
    int*   oc1      = (int*)take((size_t)CAP1 * 3 * 4);
    int*   oc2      = (int*)take((size_t)CAP2 * 3 * 4);
    unsigned short* fA1 = (unsigned short*)take((size_t)CAP1 * C1 * 2);
    int*   lut1     = (int*)take((size_t)CELLS1 * 4);
    int*   lut2     = (int*)take((size_t)CELLS2 * 4);
    unsigned short* wp_d1  = (unsigned short*)take((size_t)27 * 16 * 32 * 2);
    unsigned short* wp_r1  = (unsigned short*)take((size_t)108 * 32 * 32 * 2);
    unsigned short* wp_d2  = (unsigned short*)take((size_t)27 * 32 * 128 * 2);
    unsigned short* wp_r2  = (unsigned short*)take((size_t)108 * 128 * 128 * 2);
    unsigned short* wp_out = (unsigned short*)take((size_t)27 * 128 * 128 * 2);

    // init
    hipMemsetAsync(d_out, 0, (size_t)out_size * 4, stream);
    hipMemsetAsync(lut0, 0xFF, (size_t)CELLS0 * 4, stream);
    hipMemsetAsync(om1, 0, (size_t)CELLS1 * 4, stream);
    hipMemsetAsync(om2, 0, (size_t)CELLS2 * 4, stream);
    hipMemsetAsync(lut1, 0xFF, (size_t)CELLS1 * 4, stream);
    hipMemsetAsync(lut2, 0xFF, (size_t)CELLS2 * 4, stream);

    const int gN  = (NN + 255) / 256;
    const int gB1 = CELLS1 / 1024;        // 1225
    const int gB2 = CELLS2 / 1024;        // 154
    const int gM1 = (CAP1 + 127) / 128;   // 2735
    const int gM2 = (CAP2 + 127) / 128;   // 540
    const int gS1 = (CAP1 + 255) / 256;
    const int gS2 = (CAP2 + 255) / 256;

    // weight pre-pack (fragment order, bf16)
    k_prepack<<<(27*16*32   + 255)/256, 256, 0, stream>>>(w_d1,  wp_d1, 27, 16, 32);
    k_prepack<<<(108*32*32  + 255)/256, 256, 0, stream>>>(w_r1,  wp_r1, 108, 32, 32);
    k_prepack<<<(27*32*128  + 255)/256, 256, 0, stream>>>(w_d2,  wp_d2, 27, 32, 128);
    k_prepack<<<(108*128*128+ 255)/256, 256, 0, stream>>>(w_r2,  wp_r2, 108, 128, 128);
    k_prepack<<<(27*128*128 + 255)/256, 256, 0, stream>>>(w_out, wp_out, 27, 128, 128);

    k_init<<<gN, 256, 0, stream>>>(vf, coors, x_att, lut0, om1);
    k_attn<<<NRR, 256, 0, stream>>>(x_att, coors, et, at, wq, bq, wk_, bk, wv, bv);
    k_f0<<<gN, 256, 0, stream>>>(coors, x_att, w_in, b_in, gin_g, gin_b, f0);

    // level-1 active set
    k_blocksum<<<gB1, 256, 0, stream>>>(om1, partials, CELLS1);
    k_scanparts<<<1, 256, 0, stream>>>(partials, gB1, cnt, CAP1);
    k_emit<<<gB1, 256, 0, stream>>>(om1, partials, oc1, CELLS1, S1_1, S1_2, CAP1);

    // down conv 1 (16 -> 32)
    k_mconv<16, 32, S0_0, S0_1, S0_2, true, 0><<<gM1, 256, 0, stream>>>(
        f0, lut0, oc1, cnt, wp_d1, bn_d1, nullptr, nullptr, nullptr, fA1);
    k_lutscatter<<<gS1, 256, 0, stream>>>(oc1, cnt, lut1, S1_1, S1_2);

    // resblocks level 1 (32 ch)
    k_mconv<32, 32, S1_0, S1_1, S1_2, false, 0><<<gM1, 256, 0, stream>>>(
        fA1, lut1, oc1, cnt, wp_r1 + 0 * 27648, bn_r1 + 0 * 128, nullptr, nullptr, nullptr, fB1);
    k_mconv<32, 32, S1_0, S1_1, S1_2, false, 1><<<gM1, 256, 0, stream>>>(
        fB1, lut1, oc1, cnt, wp_r1 + 1 * 27648, bn_r1 + 1 * 128, nullptr, nullptr, fA1, fA1);
    k_mconv<32, 32, S1_0, S1_1, S1_2, false, 0><<<gM1, 256, 0, stream>>>(
        fA1, lut1, oc1, cnt, wp_r1 + 2 * 27648, bn_r1 + 2 * 128, nullptr, nullptr, nullptr, fB1);
    k_mconv<32, 32, S1_0, S1_1, S1_2, false, 1><<<gM1, 256, 0, stream>>>(
        fB1, lut1, oc1, cnt, wp_r1 + 3 * 27648, bn_r1 + 3 * 128, nullptr, nullptr, fA1, fA1);

    // level-2 active set
    k_mask2<<<gS1, 256, 0, stream>>>(oc1, cnt, om2);
    k_blocksum<<<gB2, 256, 0, stream>>>(om2, partials, CELLS2);
    k_scanparts<<<1, 256, 0, stream>>>(partials, gB2, cnt + 1, CAP2);
    k_emit<<<gB2, 256, 0, stream>>>(om2, partials, oc2, CELLS2, S2_1, S2_2, CAP2);

    // down conv 2 (32 -> 128)
    k_mconv<32, 128, S1_0, S1_1, S1_2, true, 0><<<gM2, 256, 0, stream>>>(
        fA1, lut1, oc2, cnt + 1, wp_d2, bn_d2, nullptr, nullptr, nullptr, fA2);
    k_lutscatter<<<gS2, 256, 0, stream>>>(oc2, cnt + 1, lut2, S2_1, S2_2);

    // resblocks level 2 (128 ch)
    const size_t wr2s = (size_t)27 * 128 * 128;
    k_mconv<128, 128, S2_0, S2_1, S2_2, false, 0><<<gM2, 256, 0, stream>>>(
        fA2, lut2, oc2, cnt + 1, wp_r2 + 0 * wr2s, bn_r2 + 0 * 512, nullptr, nullptr, nullptr, fB2);
    k_mconv<128, 128, S2_0, S2_1, S2_2, false, 1><<<gM2, 256, 0, stream>>>(
        fB2, lut2, oc2, cnt + 1, wp_r2 + 1 * wr2s, bn_r2 + 1 * 512, nullptr, nullptr, fA2, fA2);
    k_mconv<128, 128, S2_0, S2_1, S2_2, false, 0><<<gM2, 256, 0, stream>>>(
        fA2, lut2, oc2, cnt + 1, wp_r2 + 2 * wr2s, bn_r2 + 2 * 512, nullptr, nullptr, nullptr, fB2);
    k_mconv<128, 128, S2_0, S2_1, S2_2, false, 1><<<gM2, 256, 0, stream>>>(
        fB2, lut2, oc2, cnt + 1, wp_r2 + 3 * wr2s, bn_r2 + 3 * 512, nullptr, nullptr, fA2, fA2);

    // out conv + bias + gn16 + relu + transposed scatter (fp32)
    k_mconv<128, 128, S2_0, S2_1, S2_2, false, 2><<<gM2, 256, 0, stream>>>(
        fA2, lut2, oc2, cnt + 1, wp_out, b_out, gout_g, gout_b, nullptr, (float*)d_out);
}

// Round 3
// 1206.843 us; speedup vs baseline: 6.9372x; 1.2463x over previous
//
#include <hip/hip_runtime.h>
#include <math.h>

#define NRR 175
#define KK 250
#define NN (NRR*KK)

#define S0_0 56
#define S0_1 350
#define S0_2 512
#define S1_0 28
#define S1_1 175
#define S1_2 256
#define S2_0 14
#define S2_1 88
#define S2_2 128
#define CAP1 350000
#define CAP2 69000
#define C1 32
#define C2 128

#define CELLS0 (S0_0*S0_1*S0_2)   // 10035200
#define CELLS1 (S1_0*S1_1*S1_2)   // 1254400
#define CELLS2 (S2_0*S2_1*S2_2)   // 157696

#define ATT_SCALE 0.17677669529663687f

typedef __attribute__((ext_vector_type(8))) __bf16 bf16x8;
typedef __attribute__((ext_vector_type(16))) float f32x16;

// ---------- bf16 helpers (RNE) ----------
__device__ __forceinline__ unsigned short f2b(float x) {
    unsigned int u = __builtin_bit_cast(unsigned int, x);
    unsigned int r = u + 0x7FFFu + ((u >> 16) & 1u);
    return (unsigned short)(r >> 16);
}
__device__ __forceinline__ float b2f(unsigned short h) {
    return __builtin_bit_cast(float, (unsigned int)h << 16);
}

// ---------- helpers ----------
__device__ __forceinline__ int block_incl_scan(int v, int* s) {
    int t = threadIdx.x;
    s[t] = v; __syncthreads();
    #pragma unroll
    for (int d = 1; d < 256; d <<= 1) {
        int x = (t >= d) ? s[t - d] : 0;
        __syncthreads();
        s[t] += x;
        __syncthreads();
    }
    return s[t];
}

__device__ __forceinline__ void cand(int p, int So, int* o, int& no) {
    no = 0;
    if ((p & 1) == 0) {
        int q = p >> 1; if (q < So) o[no++] = q;
    } else {
        int q = (p - 1) >> 1; if (q < So) o[no++] = q;
        q = (p + 1) >> 1;     if (q < So) o[no++] = q;
    }
}

// ---------- stage kernels ----------
__global__ __launch_bounds__(256) void k_init(const float* __restrict__ vf,
                                              const int* __restrict__ coors,
                                              float* __restrict__ x,
                                              int* __restrict__ lut0,
                                              int* __restrict__ om1) {
    int i = blockIdx.x * 256 + threadIdx.x;
    if (i >= NN) return;
    x[i] = log10f(vf[i * 2]);
    int c1 = coors[i * 4 + 1], c2 = coors[i * 4 + 2], c3 = coors[i * 4 + 3];
    int e = 2 * c1 - 9, rg = 2 * c2, az = 2 * c3 + 149;
    atomicMax(&lut0[(e * S0_1 + rg) * S0_2 + az], i);
    int A[2], B[2], C[2]; int na, nb, nc;
    cand(e, S1_0, A, na); cand(rg, S1_1, B, nb); cand(az, S1_2, C, nc);
    for (int ia = 0; ia < na; ia++)
        for (int ib = 0; ib < nb; ib++)
            for (int ic = 0; ic < nc; ic++)
                om1[(A[ia] * S1_1 + B[ib]) * S1_2 + C[ic]] = 1;
}

// ---------- MFMA attention ----------
// One block per radar row (175 blocks, 256 threads = 4 waves).
// Per layer: S^T = K(250x32) . Q^T(32x250) via mfma_32x32x16_bf16 with hi/lo
// bf16 split (3 products, ~2^-16 relative error). Wave w owns queries
// w*64..w*64+63 (its own threads), so Q fragments are built by in-wave shfl
// (no LDS). K hi/lo staged in LDS, row stride 40 ushorts -> fragment b128
// reads are bank-uniform. Online softmax over 8 chunks of 32 keys using the
// C-layout (col=query=lane&31, row=key=(r&3)+8*(r>>2)+4*half).
#define QS 40
__global__ __launch_bounds__(256, 1) void k_attn(float* __restrict__ x_io,
    const int* __restrict__ coors,
    const float* __restrict__ et, const float* __restrict__ at,
    const float* __restrict__ wq, const float* __restrict__ bq,
    const float* __restrict__ wk, const float* __restrict__ bk,
    const float* __restrict__ wv, const float* __restrict__ bv) {
    __shared__ float xin[KK * 7];
    __shared__ unsigned short ksh_h[256 * QS];
    __shared__ unsigned short ksh_l[256 * QS];
    __shared__ float vsh[256];
    const int r = blockIdx.x;
    const int t = threadIdx.x;
    const int w = t >> 6, ln = t & 63, l31 = ln & 31, lh = ln >> 5;

    for (int i = t; i < KK; i += 256) {
        int gi = r * KK + i;
        xin[i * 7 + 0] = x_io[gi];
        int c1 = coors[gi * 4 + 1], c3 = coors[gi * 4 + 3];
        xin[i * 7 + 1] = et[c1 * 3 + 0]; xin[i * 7 + 2] = et[c1 * 3 + 1]; xin[i * 7 + 3] = et[c1 * 3 + 2];
        xin[i * 7 + 4] = at[c3 * 3 + 0]; xin[i * 7 + 5] = at[c3 * 3 + 1]; xin[i * 7 + 6] = at[c3 * 3 + 2];
    }
    __syncthreads();

    union U8 { bf16x8 v; unsigned short u[8]; };

    for (int l = 0; l < 4; l++) {
        const float* wql = wq + l * 7 * 32; const float* bql = bq + l * 32;
        const float* wkl = wk + l * 7 * 32; const float* bkl = bk + l * 32;
        const float* wvl = wv + l * 7;      const float  bvl = bv[l];
        float qh_f[32], ql_f[32];
        if (t < KK) {
            float xi[7];
            #pragma unroll
            for (int ci = 0; ci < 7; ci++) xi[ci] = xin[t * 7 + ci];
            float av = bvl;
            #pragma unroll
            for (int ci = 0; ci < 7; ci++) av += xi[ci] * wvl[ci];
            vsh[t] = av;
            #pragma unroll
            for (int d = 0; d < 32; d++) {
                float aq = bql[d], ak = bkl[d];
                #pragma unroll
                for (int ci = 0; ci < 7; ci++) { aq += xi[ci] * wql[ci * 32 + d]; ak += xi[ci] * wkl[ci * 32 + d]; }
                aq *= ATT_SCALE;
                float h = b2f(f2b(aq));
                qh_f[d] = h; ql_f[d] = aq - h;
                unsigned short k16 = f2b(ak);
                ksh_h[t * QS + d] = k16;
                ksh_l[t * QS + d] = f2b(ak - b2f(k16));
            }
        } else {
            #pragma unroll
            for (int d = 0; d < 32; d++) {
                qh_f[d] = 0.f; ql_f[d] = 0.f;
                ksh_h[t * QS + d] = 0; ksh_l[t * QS + d] = 0;
            }
            vsh[t] = 0.f;
        }
        __syncthreads();

        // Build Q fragments (B operand) by in-wave shfl from the producer lane.
        U8 Bh[2][2], Bl[2][2];
        #pragma unroll
        for (int b = 0; b < 2; b++) {
            int src = b * 32 + l31;
            #pragma unroll
            for (int ks = 0; ks < 2; ks++) {
                #pragma unroll
                for (int j = 0; j < 8; j++) {
                    float h0 = __shfl(qh_f[ks * 16 + j],     src, 64);
                    float h1 = __shfl(qh_f[ks * 16 + 8 + j], src, 64);
                    float l0 = __shfl(ql_f[ks * 16 + j],     src, 64);
                    float l1 = __shfl(ql_f[ks * 16 + 8 + j], src, 64);
                    Bh[b][ks].u[j] = f2b(lh ? h1 : h0);
                    Bl[b][ks].u[j] = f2b(lh ? l1 : l0);
                }
            }
        }

        float m[2]  = {-1e30f, -1e30f};
        float den[2] = {0.f, 0.f};
        float num[2] = {0.f, 0.f};

        for (int mt = 0; mt < 8; mt++) {
            U8 Ah[2], Al[2];
            int krow = mt * 32 + l31;
            #pragma unroll
            for (int ks = 0; ks < 2; ks++) {
                Ah[ks].v = *(const bf16x8*)&ksh_h[krow * QS + ks * 16 + lh * 8];
                Al[ks].v = *(const bf16x8*)&ksh_l[krow * QS + ks * 16 + lh * 8];
            }
            float4 v4[4];
            #pragma unroll
            for (int c = 0; c < 4; c++)
                v4[c] = *(const float4*)&vsh[mt * 32 + 8 * c + 4 * lh];

            #pragma unroll
            for (int b = 0; b < 2; b++) {
                f32x16 acc;
                #pragma unroll
                for (int q = 0; q < 16; q++) acc[q] = 0.f;
                acc = __builtin_amdgcn_mfma_f32_32x32x16_bf16(Ah[0].v, Bh[b][0].v, acc, 0, 0, 0);
                acc = __builtin_amdgcn_mfma_f32_32x32x16_bf16(Ah[1].v, Bh[b][1].v, acc, 0, 0, 0);
                acc = __builtin_amdgcn_mfma_f32_32x32x16_bf16(Ah[0].v, Bl[b][0].v, acc, 0, 0, 0);
                acc = __builtin_amdgcn_mfma_f32_32x32x16_bf16(Ah[1].v, Bl[b][1].v, acc, 0, 0, 0);
                acc = __builtin_amdgcn_mfma_f32_32x32x16_bf16(Al[0].v, Bh[b][0].v, acc, 0, 0, 0);
                acc = __builtin_amdgcn_mfma_f32_32x32x16_bf16(Al[1].v, Bh[b][1].v, acc, 0, 0, 0);

                float s[16];
                #pragma unroll
                for (int rr = 0; rr < 16; rr++) {
                    s[rr] = acc[rr];
                    if (mt == 7) {
                        int key = 224 + (rr & 3) + 8 * (rr >> 2) + 4 * lh;
                        if (key >= KK) s[rr] = -1e30f;
                    }
                }
                float cm = s[0];
                #pragma unroll
                for (int rr = 1; rr < 16; rr++) cm = fmaxf(cm, s[rr]);
                cm = fmaxf(cm, __shfl_xor(cm, 32, 64));
                float mn = fmaxf(m[b], cm);
                float alpha = __expf(m[b] - mn);
                float dsum = 0.f, nsum = 0.f;
                #pragma unroll
                for (int rr = 0; rr < 16; rr++) {
                    float e = __expf(s[rr] - mn);
                    dsum += e;
                    nsum += e * ((&v4[rr >> 2].x)[rr & 3]);
                }
                den[b] = den[b] * alpha + dsum;
                num[b] = num[b] * alpha + nsum;
                m[b] = mn;
            }
        }
        __syncthreads();
        #pragma unroll
        for (int b = 0; b < 2; b++) {
            float dtot = den[b] + __shfl_xor(den[b], 32, 64);
            float ntot = num[b] + __shfl_xor(num[b], 32, 64);
            int q = (w * 2 + b) * 32 + l31;
            if (lh == 0 && q < KK) xin[q * 7] = ntot / dtot;
        }
        __syncthreads();
    }
    for (int i = t; i < KK; i += 256) x_io[r * KK + i] = xin[i * 7];
}

__global__ __launch_bounds__(256) void k_f0(const int* __restrict__ coors,
    const float* __restrict__ x,
    const float* __restrict__ w_in, const float* __restrict__ b_in,
    const float* __restrict__ gg, const float* __restrict__ gb,
    unsigned short* __restrict__ f0) {
    int i = blockIdx.x * 256 + threadIdx.x;
    if (i >= NN) return;
    int c1 = coors[i * 4 + 1], c2 = coors[i * 4 + 2], c3 = coors[i * 4 + 3];
    float fe0 = (float)(2 * c1 - 9), fe1 = (float)(2 * c2), fe2 = (float)(2 * c3 + 149), fe3 = x[i];
    float tv[16];
    #pragma unroll
    for (int c = 0; c < 16; c++)
        tv[c] = b_in[c] + fe0 * w_in[c] + fe1 * w_in[16 + c] + fe2 * w_in[32 + c] + fe3 * w_in[48 + c];
    #pragma unroll
    for (int g = 0; g < 8; g++) {
        float a = tv[2 * g], b = tv[2 * g + 1];
        float m = 0.5f * (a + b);
        float va = 0.5f * ((a - m) * (a - m) + (b - m) * (b - m));
        float inv = rsqrtf(va + 1e-5f);
        f0[i * 16 + 2 * g]     = f2b(fmaxf((a - m) * inv * gg[2 * g]     + gb[2 * g],     0.f));
        f0[i * 16 + 2 * g + 1] = f2b(fmaxf((b - m) * inv * gg[2 * g + 1] + gb[2 * g + 1], 0.f));
    }
}

__global__ __launch_bounds__(256) void k_blocksum(const int* __restrict__ om,
                                                  int* __restrict__ partials, int ncells) {
    __shared__ int sh[256];
    int t = threadIdx.x;
    int base = blockIdx.x * 1024 + t * 4;
    int s = 0;
    #pragma unroll
    for (int q = 0; q < 4; q++) s += (base + q < ncells) ? om[base + q] : 0;
    int incl = block_incl_scan(s, sh);
    if (t == 255) partials[blockIdx.x] = incl;
}

__global__ __launch_bounds__(256) void k_scanparts(int* __restrict__ partials, int nparts,
                                                   int* __restrict__ pcnt, int cap) {
    __shared__ int sh[256];
    __shared__ int tot;
    int t = threadIdx.x;
    int chunk = (nparts + 255) / 256;
    int beg = t * chunk;
    int vals[8];
    int s = 0;
    #pragma unroll
    for (int i = 0; i < 8; i++) {
        if (i < chunk) {
            int ix = beg + i;
            int x = (ix < nparts) ? partials[ix] : 0;
            vals[i] = x; s += x;
        }
    }
    int incl = block_incl_scan(s, sh);
    int excl = incl - s;
    if (t == 255) tot = incl;
    int run = excl;
    #pragma unroll
    for (int i = 0; i < 8; i++) {
        if (i < chunk) {
            int ix = beg + i;
            if (ix < nparts) { partials[ix] = run; run += vals[i]; }
        }
    }
    __syncthreads();
    if (t == 0) *pcnt = min(tot, cap);
}

__global__ __launch_bounds__(256) void k_emit(const int* __restrict__ om,
                                              const int* __restrict__ partials,
                                              int* __restrict__ oc,
                                              int ncells, int D1, int D2, int cap) {
    __shared__ int sh[256];
    int t = threadIdx.x;
    int base = blockIdx.x * 1024 + t * 4;
    int v[4]; int s = 0;
    #pragma unroll
    for (int q = 0; q < 4; q++) { v[q] = (base + q < ncells) ? om[base + q] : 0; s += v[q]; }
    int incl = block_incl_scan(s, sh);
    int run = partials[blockIdx.x] + (incl - s);
    int D12 = D1 * D2;
    #pragma unroll
    for (int q = 0; q < 4; q++) {
        if (v[q]) {
            if (run < cap) {
                int lin = base + q;
                int i0 = lin / D12;
                int r2 = lin - i0 * D12;
                int i1 = r2 / D2;
                int i2 = r2 - i1 * D2;
                oc[run * 3] = i0; oc[run * 3 + 1] = i1; oc[run * 3 + 2] = i2;
            }
            run++;
        }
    }
}

__global__ __launch_bounds__(256) void k_lutscatter(const int* __restrict__ oc,
                                                    const int* __restrict__ pc,
                                                    int* __restrict__ lut, int D1, int D2) {
    int j = blockIdx.x * 256 + threadIdx.x;
    if (j >= *pc) return;
    lut[(oc[j * 3] * D1 + oc[j * 3 + 1]) * D2 + oc[j * 3 + 2]] = j;
}

__global__ __launch_bounds__(256) void k_mask2(const int* __restrict__ oc,
                                               const int* __restrict__ pc,
                                               int* __restrict__ om) {
    int j = blockIdx.x * 256 + threadIdx.x;
    if (j >= *pc) return;
    int p0 = oc[j * 3], p1 = oc[j * 3 + 1], p2 = oc[j * 3 + 2];
    int A[2], B[2], C[2]; int na, nb, nc;
    cand(p0, S2_0, A, na); cand(p1, S2_1, B, nb); cand(p2, S2_2, C, nc);
    for (int ia = 0; ia < na; ia++)
        for (int ib = 0; ib < nb; ib++)
            for (int ic = 0; ic < nc; ic++)
                om[(A[ia] * S2_1 + B[ib]) * S2_2 + C[ic]] = 1;
}

// ---------- weight pre-pack into MFMA B-fragment order ----------
__global__ __launch_bounds__(256) void k_prepack(const float* __restrict__ w,
        unsigned short* __restrict__ wp, int nk, int cin, int cout) {
    int tid = blockIdx.x * 256 + threadIdx.x;
    int tot = nk * cin * cout;
    if (tid >= tot) return;
    int co = tid % cout; int rest = tid / cout; int ci = rest % cin; int kk = rest / cin;
    int ks = ci >> 4, kr = ci & 15, half = kr >> 3, j = kr & 7;
    int nt = co >> 5, cl = co & 31, lane = half * 32 + cl;
    wp[((((size_t)kk * (cin >> 4) + ks) * (cout >> 5) + nt) * 64 + lane) * 8 + j] = f2b(w[tid]);
}

// ---------- MFMA gather-conv ----------
template<int CIN, int COUT, int SD0, int SD1, int SD2, bool DOWN, int MODE>
__global__ __launch_bounds__(256, 2)
void k_mconv(const unsigned short* __restrict__ fin, const int* __restrict__ lut,
             const int* __restrict__ oc, const int* __restrict__ pc,
             const unsigned short* __restrict__ wp,
             const float* __restrict__ p0, const float* __restrict__ p1,
             const float* __restrict__ p2,
             const unsigned short* __restrict__ res, void* __restrict__ fout_) {
    constexpr int KS = CIN / 16;
    constexpr int NT = COUT / 32;
    constexpr int SROW = CIN + 8;
    constexpr int CPR = CIN / 8;
    constexpr int TM = (COUT == 128) ? 2 : 1;
    constexpr int TN = (COUT == 128) ? 2 : 1;
    __shared__ unsigned short sA[128 * SROW];
    __shared__ int sidx[128];
    __shared__ int sc[128 * 3];

    const int n = *pc;
    const int j0 = blockIdx.x * 128;
    if (j0 >= n) return;
    const int t = threadIdx.x;
    const int w = t >> 6;
    const int ln = t & 63;
    const int l31 = ln & 31;
    const int lh = ln >> 5;
    const int rowbase = (COUT == 128) ? (w & 1) * 64 : w * 32;
    const int colt0  = (COUT == 128) ? (w >> 1) * TN : 0;

    for (int i = t; i < 128 * 3; i += 256) {
        int j = j0 + i / 3;
        sc[i] = (j < n) ? oc[j * 3 + (i % 3)] : -1000000;
    }
    __syncthreads();

    f32x16 acc[TM][TN];
    #pragma unroll
    for (int a = 0; a < TM; a++)
        #pragma unroll
        for (int b = 0; b < TN; b++)
            #pragma unroll
            for (int q = 0; q < 16; q++) acc[a][b][q] = 0.f;

    for (int k = 0; k < 27; k++) {
        const int dx = k / 9 - 1, dy = (k / 3) % 3 - 1, dz = k % 3 - 1;
        if (t < 128) {
            int x = sc[t * 3], y = sc[t * 3 + 1], z = sc[t * 3 + 2];
            if (DOWN) { x = 2 * x + dx; y = 2 * y + dy; z = 2 * z + dz; }
            else      { x += dx; y += dy; z += dz; }
            int idx = -1;
            if ((unsigned)x < (unsigned)SD0 && (unsigned)y < (unsigned)SD1 && (unsigned)z < (unsigned)SD2)
                idx = lut[(x * SD1 + y) * SD2 + z];
            sidx[t] = idx;
        }
        __syncthreads();
        #pragma unroll
        for (int it = 0; it < (128 * CPR) / 256; it++) {
            int cc = t + it * 256;
            int r = cc / CPR, c = cc % CPR;
            int idx = sidx[r];
            uint4 v = make_uint4(0, 0, 0, 0);
            if (idx >= 0) v = *(const uint4*)(fin + (size_t)idx * CIN + c * 8);
            *(uint4*)(&sA[r * SROW + c * 8]) = v;
        }
        __syncthreads();
        const unsigned short* wk = wp + (size_t)k * KS * NT * 512;
        #pragma unroll
        for (int ks = 0; ks < KS; ks++) {
            bf16x8 afr[TM], bfr[TN];
            #pragma unroll
            for (int a = 0; a < TM; a++)
                afr[a] = *(const bf16x8*)(&sA[(rowbase + a * 32 + l31) * SROW + ks * 16 + lh * 8]);
            #pragma unroll
            for (int b = 0; b < TN; b++)
                bfr[b] = *(const bf16x8*)(wk + ((size_t)(ks * NT + colt0 + b) * 64 + ln) * 8);
            #pragma unroll
            for (int a = 0; a < TM; a++)
                #pragma unroll
                for (int b = 0; b < TN; b++)
                    acc[a][b] = __builtin_amdgcn_mfma_f32_32x32x16_bf16(afr[a], bfr[b], acc[a][b], 0, 0, 0);
        }
        __syncthreads();
    }

    if (MODE != 2) {
        unsigned short* fout = (unsigned short*)fout_;
        #pragma unroll
        for (int b = 0; b < TN; b++) {
            int co = (colt0 + b) * 32 + l31;
            float g_ = p0[co], bb_ = p0[COUT + co], m_ = p0[2 * COUT + co];
            float iv = rsqrtf(p0[3 * COUT + co] + 1e-3f);
            #pragma unroll
            for (int a = 0; a < TM; a++) {
                #pragma unroll
                for (int r = 0; r < 16; r++) {
                    int jr = rowbase + a * 32 + (r & 3) + 8 * (r >> 2) + 4 * lh;
                    int j = j0 + jr;
                    if (j < n) {
                        float y = (acc[a][b][r] - m_) * iv * g_ + bb_;
                        if (MODE == 1) y += b2f(res[(size_t)j * COUT + co]);
                        fout[(size_t)j * COUT + co] = f2b(fmaxf(y, 0.f));
                    }
                }
            }
        }
    } else {
        float* dout = (float*)fout_;
        #pragma unroll
        for (int b = 0; b < TN; b++) {
            int co = (colt0 + b) * 32 + l31;
            float bias = p0[co], gg_ = p1[co], gb_ = p2[co];
            #pragma unroll
            for (int a = 0; a < TM; a++) {
                #pragma unroll
                for (int r = 0; r < 16; r++) {
                    int jr = rowbase + a * 32 + (r & 3) + 8 * (r >> 2) + 4 * lh;
                    int j = j0 + jr;
                    float y = acc[a][b][r] + bias;
                    float s = y;
                    s += __shfl_xor(s, 1, 8);
                    s += __shfl_xor(s, 2, 8);
                    s += __shfl_xor(s, 4, 8);
                    float m = s * 0.125f;
                    float d = y - m;
                    float q2 = d * d;
                    q2 += __shfl_xor(q2, 1, 8);
                    q2 += __shfl_xor(q2, 2, 8);
                    q2 += __shfl_xor(q2, 4, 8);
                    float var = q2 * 0.125f;
                    float o = fmaxf(d * rsqrtf(var + 1e-5f) * gg_ + gb_, 0.f);
                    if (j < n) {
                        int aa = sc[jr * 3], bb = sc[jr * 3 + 1], cc = sc[jr * 3 + 2];
                        dout[(((size_t)co * S2_2 + cc) * S2_1 + bb) * S2_0 + aa] = o;
                    }
                }
            }
        }
    }
}

// ---------- host ----------
extern "C" void kernel_launch(void* const* d_in, const int* in_sizes, int n_in,
                              void* d_out, int out_size, void* d_ws, size_t ws_size,
                              hipStream_t stream) {
    const float* vf    = (const float*)d_in[0];
    const int*   coors = (const int*)d_in[1];
    const float* et    = (const float*)d_in[3];
    const float* at    = (const float*)d_in[4];
    const float* wq    = (const float*)d_in[5];
    const float* bq    = (const float*)d_in[6];
    const float* wk_   = (const float*)d_in[7];
    const float* bk    = (const float*)d_in[8];
    const float* wv    = (const float*)d_in[9];
    const float* bv    = (const float*)d_in[10];
    const float* w_in  = (const float*)d_in[11];
    const float* b_in  = (const float*)d_in[12];
    const float* gin_g = (const float*)d_in[13];
    const float* gin_b = (const float*)d_in[14];
    const float* w_d1  = (const float*)d_in[15];
    const float* bn_d1 = (const float*)d_in[16];
    const float* w_r1  = (const float*)d_in[17];
    const float* bn_r1 = (const float*)d_in[18];
    const float* w_d2  = (const float*)d_in[19];
    const float* bn_d2 = (const float*)d_in[20];
    const float* w_r2  = (const float*)d_in[21];
    const float* bn_r2 = (const float*)d_in[22];
    const float* w_out = (const float*)d_in[23];
    const float* b_out = (const float*)d_in[24];
    const float* gout_g= (const float*)d_in[25];
    const float* gout_b= (const float*)d_in[26];

    char* ws = (char*)d_ws;
    size_t cur = 0;
    auto take = [&](size_t bytes) -> char* {
        char* p = ws + cur;
        cur += (bytes + 255) & ~(size_t)255;
        return p;
    };
    char* U = take((size_t)4194304 + (size_t)CELLS0 * 4);
    float*          x_att = (float*)U;
    unsigned short* f0    = (unsigned short*)(U + 262144);
    int*            lut0  = (int*)(U + 4194304);
    unsigned short* fB1   = (unsigned short*)U;
    unsigned short* fA2   = (unsigned short*)U;
    unsigned short* fB2   = (unsigned short*)(U + 17694720);

    int*   om1      = (int*)take((size_t)CELLS1 * 4);
    int*   om2      = (int*)take((size_t)CELLS2 * 4);
    int*   partials = (int*)take(8192);
    int*   cnt      = (int*)take(256);
    int*   oc1      = (int*)take((size_t)CAP1 * 3 * 4);
    int*   oc2      = (int*)take((size_t)CAP2 * 3 * 4);
    unsigned short* fA1 = (unsigned short*)take((size_t)CAP1 * C1 * 2);
    int*   lut1     = (int*)take((size_t)CELLS1 * 4);
    int*   lut2     = (int*)take((size_t)CELLS2 * 4);
    unsigned short* wp_d1  = (unsigned short*)take((size_t)27 * 16 * 32 * 2);
    unsigned short* wp_r1  = (unsigned short*)take((size_t)108 * 32 * 32 * 2);
    unsigned short* wp_d2  = (unsigned short*)take((size_t)27 * 32 * 128 * 2);
    unsigned short* wp_r2  = (unsigned short*)take((size_t)108 * 128 * 128 * 2);
    unsigned short* wp_out = (unsigned short*)take((size_t)27 * 128 * 128 * 2);

    hipMemsetAsync(d_out, 0, (size_t)out_size * 4, stream);
    hipMemsetAsync(lut0, 0xFF, (size_t)CELLS0 * 4, stream);
    hipMemsetAsync(om1, 0, (size_t)CELLS1 * 4, stream);
    hipMemsetAsync(om2, 0, (size_t)CELLS2 * 4, stream);
    hipMemsetAsync(lut1, 0xFF, (size_t)CELLS1 * 4, stream);
    hipMemsetAsync(lut2, 0xFF, (size_t)CELLS2 * 4, stream);

    const int gN  = (NN + 255) / 256;
    const int gB1 = CELLS1 / 1024;
    const int gB2 = CELLS2 / 1024;
    const int gM1 = (CAP1 + 127) / 128;
    const int gM2 = (CAP2 + 127) / 128;
    const int gS1 = (CAP1 + 255) / 256;
    const int gS2 = (CAP2 + 255) / 256;

    k_prepack<<<(27*16*32   + 255)/256, 256, 0, stream>>>(w_d1,  wp_d1, 27, 16, 32);
    k_prepack<<<(108*32*32  + 255)/256, 256, 0, stream>>>(w_r1,  wp_r1, 108, 32, 32);
    k_prepack<<<(27*32*128  + 255)/256, 256, 0, stream>>>(w_d2,  wp_d2, 27, 32, 128);
    k_prepack<<<(108*128*128+ 255)/256, 256, 0, stream>>>(w_r2,  wp_r2, 108, 128, 128);
    k_prepack<<<(27*128*128 + 255)/256, 256, 0, stream>>>(w_out, wp_out, 27, 128, 128);

    k_init<<<gN, 256, 0, stream>>>(vf, coors, x_att, lut0, om1);
    k_attn<<<NRR, 256, 0, stream>>>(x_att, coors, et, at, wq, bq, wk_, bk, wv, bv);
    k_f0<<<gN, 256, 0, stream>>>(coors, x_att, w_in, b_in, gin_g, gin_b, f0);

    k_blocksum<<<gB1, 256, 0, stream>>>(om1, partials, CELLS1);
    k_scanparts<<<1, 256, 0, stream>>>(partials, gB1, cnt, CAP1);
    k_emit<<<gB1, 256, 0, stream>>>(om1, partials, oc1, CELLS1, S1_1, S1_2, CAP1);

    k_mconv<16, 32, S0_0, S0_1, S0_2, true, 0><<<gM1, 256, 0, stream>>>(
        f0, lut0, oc1, cnt, wp_d1, bn_d1, nullptr, nullptr, nullptr, fA1);
    k_lutscatter<<<gS1, 256, 0, stream>>>(oc1, cnt, lut1, S1_1, S1_2);

    k_mconv<32, 32, S1_0, S1_1, S1_2, false, 0><<<gM1, 256, 0, stream>>>(
        fA1, lut1, oc1, cnt, wp_r1 + 0 * 27648, bn_r1 + 0 * 128, nullptr, nullptr, nullptr, fB1);
    k_mconv<32, 32, S1_0, S1_1, S1_2, false, 1><<<gM1, 256, 0, stream>>>(
        fB1, lut1, oc1, cnt, wp_r1 + 1 * 27648, bn_r1 + 1 * 128, nullptr, nullptr, fA1, fA1);
    k_mconv<32, 32, S1_0, S1_1, S1_2, false, 0><<<gM1, 256, 0, stream>>>(
        fA1, lut1, oc1, cnt, wp_r1 + 2 * 27648, bn_r1 + 2 * 128, nullptr, nullptr, nullptr, fB1);
    k_mconv<32, 32, S1_0, S1_1, S1_2, false, 1><<<gM1, 256, 0, stream>>>(
        fB1, lut1, oc1, cnt, wp_r1 + 3 * 27648, bn_r1 + 3 * 128, nullptr, nullptr, fA1, fA1);

    k_mask2<<<gS1, 256, 0, stream>>>(oc1, cnt, om2);
    k_blocksum<<<gB2, 256, 0, stream>>>(om2, partials, CELLS2);
    k_scanparts<<<1, 256, 0, stream>>>(partials, gB2, cnt + 1, CAP2);
    k_emit<<<gB2, 256, 0, stream>>>(om2, partials, oc2, CELLS2, S2_1, S2_2, CAP2);

    k_mconv<32, 128, S1_0, S1_1, S1_2, true, 0><<<gM2, 256, 0, stream>>>(
        fA1, lut1, oc2, cnt + 1, wp_d2, bn_d2, nullptr, nullptr, nullptr, fA2);
    k_lutscatter<<<gS2, 256, 0, stream>>>(oc2, cnt + 1, lut2, S2_1, S2_2);

    const size_t wr2s = (size_t)27 * 128 * 128;
    k_mconv<128, 128, S2_0, S2_1, S2_2, false, 0><<<gM2, 256, 0, stream>>>(
        fA2, lut2, oc2, cnt + 1, wp_r2 + 0 * wr2s, bn_r2 + 0 * 512, nullptr, nullptr, nullptr, fB2);
    k_mconv<128, 128, S2_0, S2_1, S2_2, false, 1><<<gM2, 256, 0, stream>>>(
        fB2, lut2, oc2, cnt + 1, wp_r2 + 1 * wr2s, bn_r2 + 1 * 512, nullptr, nullptr, fA2, fA2);
    k_mconv<128, 128, S2_0, S2_1, S2_2, false, 0><<<gM2, 256, 0, stream>>>(
        fA2, lut2, oc2, cnt + 1, wp_r2 + 2 * wr2s, bn_r2 + 2 * 512, nullptr, nullptr, nullptr, fB2);
    k_mconv<128, 128, S2_0, S2_1, S2_2, false, 1><<<gM2, 256, 0, stream>>>(
        fB2, lut2, oc2, cnt + 1, wp_r2 + 3 * wr2s, bn_r2 + 3 * 512, nullptr, nullptr, fA2, fA2);

    k_mconv<128, 128, S2_0, S2_1, S2_2, false, 2><<<gM2, 256, 0, stream>>>(
        fA2, lut2, oc2, cnt + 1, wp_out, b_out, gout_g, gout_b, nullptr, (float*)d_out);
}

// Round 4
// 1092.772 us; speedup vs baseline: 7.6613x; 1.1044x over previous
//
#include <hip/hip_runtime.h>
#include <math.h>

#define NRR 175
#define KK 250
#define NN (NRR*KK)

#define S0_0 56
#define S0_1 350
#define S0_2 512
#define S1_0 28
#define S1_1 175
#define S1_2 256
#define S2_0 14
#define S2_1 88
#define S2_2 128
#define CAP1 350000
#define CAP2 69000
#define C1 32
#define C2 128
#define FOP 69632   // fo_t row stride (padded)

#define CELLS0 (S0_0*S0_1*S0_2)   // 10035200
#define CELLS1 (S1_0*S1_1*S1_2)   // 1254400
#define CELLS2 (S2_0*S2_1*S2_2)   // 157696

#define ATT_SCALE 0.17677669529663687f

typedef __attribute__((ext_vector_type(8))) __bf16 bf16x8;
typedef __attribute__((ext_vector_type(16))) float f32x16;

// ---------- bf16 helpers (RNE) ----------
__device__ __forceinline__ unsigned short f2b(float x) {
    unsigned int u = __builtin_bit_cast(unsigned int, x);
    unsigned int r = u + 0x7FFFu + ((u >> 16) & 1u);
    return (unsigned short)(r >> 16);
}
__device__ __forceinline__ float b2f(unsigned short h) {
    return __builtin_bit_cast(float, (unsigned int)h << 16);
}

// ---------- helpers ----------
__device__ __forceinline__ int block_incl_scan(int v, int* s) {
    int t = threadIdx.x;
    s[t] = v; __syncthreads();
    #pragma unroll
    for (int d = 1; d < 256; d <<= 1) {
        int x = (t >= d) ? s[t - d] : 0;
        __syncthreads();
        s[t] += x;
        __syncthreads();
    }
    return s[t];
}

__device__ __forceinline__ void cand(int p, int So, int* o, int& no) {
    no = 0;
    if ((p & 1) == 0) {
        int q = p >> 1; if (q < So) o[no++] = q;
    } else {
        int q = (p - 1) >> 1; if (q < So) o[no++] = q;
        q = (p + 1) >> 1;     if (q < So) o[no++] = q;
    }
}

// ---------- stage kernels ----------
__global__ __launch_bounds__(256) void k_init(const float* __restrict__ vf,
                                              const int* __restrict__ coors,
                                              float* __restrict__ x,
                                              int* __restrict__ lut0,
                                              int* __restrict__ om1) {
    int i = blockIdx.x * 256 + threadIdx.x;
    if (i >= NN) return;
    x[i] = log10f(vf[i * 2]);
    int c1 = coors[i * 4 + 1], c2 = coors[i * 4 + 2], c3 = coors[i * 4 + 3];
    int e = 2 * c1 - 9, rg = 2 * c2, az = 2 * c3 + 149;
    atomicMax(&lut0[(e * S0_1 + rg) * S0_2 + az], i);
    int A[2], B[2], C[2]; int na, nb, nc;
    cand(e, S1_0, A, na); cand(rg, S1_1, B, nb); cand(az, S1_2, C, nc);
    for (int ia = 0; ia < na; ia++)
        for (int ib = 0; ib < nb; ib++)
            for (int ic = 0; ic < nc; ic++)
                om1[(A[ia] * S1_1 + B[ib]) * S1_2 + C[ic]] = 1;
}

// ---------- MFMA attention (see R3 notes) ----------
#define QS 40
__global__ __launch_bounds__(256, 1) void k_attn(float* __restrict__ x_io,
    const int* __restrict__ coors,
    const float* __restrict__ et, const float* __restrict__ at,
    const float* __restrict__ wq, const float* __restrict__ bq,
    const float* __restrict__ wk, const float* __restrict__ bk,
    const float* __restrict__ wv, const float* __restrict__ bv) {
    __shared__ float xin[KK * 7];
    __shared__ unsigned short ksh_h[256 * QS];
    __shared__ unsigned short ksh_l[256 * QS];
    __shared__ float vsh[256];
    const int r = blockIdx.x;
    const int t = threadIdx.x;
    const int w = t >> 6, ln = t & 63, l31 = ln & 31, lh = ln >> 5;

    for (int i = t; i < KK; i += 256) {
        int gi = r * KK + i;
        xin[i * 7 + 0] = x_io[gi];
        int c1 = coors[gi * 4 + 1], c3 = coors[gi * 4 + 3];
        xin[i * 7 + 1] = et[c1 * 3 + 0]; xin[i * 7 + 2] = et[c1 * 3 + 1]; xin[i * 7 + 3] = et[c1 * 3 + 2];
        xin[i * 7 + 4] = at[c3 * 3 + 0]; xin[i * 7 + 5] = at[c3 * 3 + 1]; xin[i * 7 + 6] = at[c3 * 3 + 2];
    }
    __syncthreads();

    union U8 { bf16x8 v; unsigned short u[8]; };

    for (int l = 0; l < 4; l++) {
        const float* wql = wq + l * 7 * 32; const float* bql = bq + l * 32;
        const float* wkl = wk + l * 7 * 32; const float* bkl = bk + l * 32;
        const float* wvl = wv + l * 7;      const float  bvl = bv[l];
        float qh_f[32], ql_f[32];
        if (t < KK) {
            float xi[7];
            #pragma unroll
            for (int ci = 0; ci < 7; ci++) xi[ci] = xin[t * 7 + ci];
            float av = bvl;
            #pragma unroll
            for (int ci = 0; ci < 7; ci++) av += xi[ci] * wvl[ci];
            vsh[t] = av;
            #pragma unroll
            for (int d = 0; d < 32; d++) {
                float aq = bql[d], ak = bkl[d];
                #pragma unroll
                for (int ci = 0; ci < 7; ci++) { aq += xi[ci] * wql[ci * 32 + d]; ak += xi[ci] * wkl[ci * 32 + d]; }
                aq *= ATT_SCALE;
                float h = b2f(f2b(aq));
                qh_f[d] = h; ql_f[d] = aq - h;
                unsigned short k16 = f2b(ak);
                ksh_h[t * QS + d] = k16;
                ksh_l[t * QS + d] = f2b(ak - b2f(k16));
            }
        } else {
            #pragma unroll
            for (int d = 0; d < 32; d++) {
                qh_f[d] = 0.f; ql_f[d] = 0.f;
                ksh_h[t * QS + d] = 0; ksh_l[t * QS + d] = 0;
            }
            vsh[t] = 0.f;
        }
        __syncthreads();

        U8 Bh[2][2], Bl[2][2];
        #pragma unroll
        for (int b = 0; b < 2; b++) {
            int src = b * 32 + l31;
            #pragma unroll
            for (int ks = 0; ks < 2; ks++) {
                #pragma unroll
                for (int j = 0; j < 8; j++) {
                    float h0 = __shfl(qh_f[ks * 16 + j],     src, 64);
                    float h1 = __shfl(qh_f[ks * 16 + 8 + j], src, 64);
                    float l0 = __shfl(ql_f[ks * 16 + j],     src, 64);
                    float l1 = __shfl(ql_f[ks * 16 + 8 + j], src, 64);
                    Bh[b][ks].u[j] = f2b(lh ? h1 : h0);
                    Bl[b][ks].u[j] = f2b(lh ? l1 : l0);
                }
            }
        }

        float m[2]  = {-1e30f, -1e30f};
        float den[2] = {0.f, 0.f};
        float num[2] = {0.f, 0.f};

        for (int mt = 0; mt < 8; mt++) {
            U8 Ah[2], Al[2];
            int krow = mt * 32 + l31;
            #pragma unroll
            for (int ks = 0; ks < 2; ks++) {
                Ah[ks].v = *(const bf16x8*)&ksh_h[krow * QS + ks * 16 + lh * 8];
                Al[ks].v = *(const bf16x8*)&ksh_l[krow * QS + ks * 16 + lh * 8];
            }
            float4 v4[4];
            #pragma unroll
            for (int c = 0; c < 4; c++)
                v4[c] = *(const float4*)&vsh[mt * 32 + 8 * c + 4 * lh];

            #pragma unroll
            for (int b = 0; b < 2; b++) {
                f32x16 acc;
                #pragma unroll
                for (int q = 0; q < 16; q++) acc[q] = 0.f;
                acc = __builtin_amdgcn_mfma_f32_32x32x16_bf16(Ah[0].v, Bh[b][0].v, acc, 0, 0, 0);
                acc = __builtin_amdgcn_mfma_f32_32x32x16_bf16(Ah[1].v, Bh[b][1].v, acc, 0, 0, 0);
                acc = __builtin_amdgcn_mfma_f32_32x32x16_bf16(Ah[0].v, Bl[b][0].v, acc, 0, 0, 0);
                acc = __builtin_amdgcn_mfma_f32_32x32x16_bf16(Ah[1].v, Bl[b][1].v, acc, 0, 0, 0);
                acc = __builtin_amdgcn_mfma_f32_32x32x16_bf16(Al[0].v, Bh[b][0].v, acc, 0, 0, 0);
                acc = __builtin_amdgcn_mfma_f32_32x32x16_bf16(Al[1].v, Bh[b][1].v, acc, 0, 0, 0);

                float s[16];
                #pragma unroll
                for (int rr = 0; rr < 16; rr++) {
                    s[rr] = acc[rr];
                    if (mt == 7) {
                        int key = 224 + (rr & 3) + 8 * (rr >> 2) + 4 * lh;
                        if (key >= KK) s[rr] = -1e30f;
                    }
                }
                float cm = s[0];
                #pragma unroll
                for (int rr = 1; rr < 16; rr++) cm = fmaxf(cm, s[rr]);
                cm = fmaxf(cm, __shfl_xor(cm, 32, 64));
                float mn = fmaxf(m[b], cm);
                float alpha = __expf(m[b] - mn);
                float dsum = 0.f, nsum = 0.f;
                #pragma unroll
                for (int rr = 0; rr < 16; rr++) {
                    float e = __expf(s[rr] - mn);
                    dsum += e;
                    nsum += e * ((&v4[rr >> 2].x)[rr & 3]);
                }
                den[b] = den[b] * alpha + dsum;
                num[b] = num[b] * alpha + nsum;
                m[b] = mn;
            }
        }
        __syncthreads();
        #pragma unroll
        for (int b = 0; b < 2; b++) {
            float dtot = den[b] + __shfl_xor(den[b], 32, 64);
            float ntot = num[b] + __shfl_xor(num[b], 32, 64);
            int q = (w * 2 + b) * 32 + l31;
            if (lh == 0 && q < KK) xin[q * 7] = ntot / dtot;
        }
        __syncthreads();
    }
    for (int i = t; i < KK; i += 256) x_io[r * KK + i] = xin[i * 7];
}

__global__ __launch_bounds__(256) void k_f0(const int* __restrict__ coors,
    const float* __restrict__ x,
    const float* __restrict__ w_in, const float* __restrict__ b_in,
    const float* __restrict__ gg, const float* __restrict__ gb,
    unsigned short* __restrict__ f0) {
    int i = blockIdx.x * 256 + threadIdx.x;
    if (i >= NN) return;
    int c1 = coors[i * 4 + 1], c2 = coors[i * 4 + 2], c3 = coors[i * 4 + 3];
    float fe0 = (float)(2 * c1 - 9), fe1 = (float)(2 * c2), fe2 = (float)(2 * c3 + 149), fe3 = x[i];
    float tv[16];
    #pragma unroll
    for (int c = 0; c < 16; c++)
        tv[c] = b_in[c] + fe0 * w_in[c] + fe1 * w_in[16 + c] + fe2 * w_in[32 + c] + fe3 * w_in[48 + c];
    #pragma unroll
    for (int g = 0; g < 8; g++) {
        float a = tv[2 * g], b = tv[2 * g + 1];
        float m = 0.5f * (a + b);
        float va = 0.5f * ((a - m) * (a - m) + (b - m) * (b - m));
        float inv = rsqrtf(va + 1e-5f);
        f0[i * 16 + 2 * g]     = f2b(fmaxf((a - m) * inv * gg[2 * g]     + gb[2 * g],     0.f));
        f0[i * 16 + 2 * g + 1] = f2b(fmaxf((b - m) * inv * gg[2 * g + 1] + gb[2 * g + 1], 0.f));
    }
}

__global__ __launch_bounds__(256) void k_blocksum(const int* __restrict__ om,
                                                  int* __restrict__ partials, int ncells) {
    __shared__ int sh[256];
    int t = threadIdx.x;
    int base = blockIdx.x * 1024 + t * 4;
    int s = 0;
    #pragma unroll
    for (int q = 0; q < 4; q++) s += (base + q < ncells) ? om[base + q] : 0;
    int incl = block_incl_scan(s, sh);
    if (t == 255) partials[blockIdx.x] = incl;
}

__global__ __launch_bounds__(256) void k_scanparts(int* __restrict__ partials, int nparts,
                                                   int* __restrict__ pcnt, int cap) {
    __shared__ int sh[256];
    __shared__ int tot;
    int t = threadIdx.x;
    int chunk = (nparts + 255) / 256;
    int beg = t * chunk;
    int vals[8];
    int s = 0;
    #pragma unroll
    for (int i = 0; i < 8; i++) {
        if (i < chunk) {
            int ix = beg + i;
            int x = (ix < nparts) ? partials[ix] : 0;
            vals[i] = x; s += x;
        }
    }
    int incl = block_incl_scan(s, sh);
    int excl = incl - s;
    if (t == 255) tot = incl;
    int run = excl;
    #pragma unroll
    for (int i = 0; i < 8; i++) {
        if (i < chunk) {
            int ix = beg + i;
            if (ix < nparts) { partials[ix] = run; run += vals[i]; }
        }
    }
    __syncthreads();
    if (t == 0) *pcnt = min(tot, cap);
}

__global__ __launch_bounds__(256) void k_emit(const int* __restrict__ om,
                                              const int* __restrict__ partials,
                                              int* __restrict__ oc,
                                              int ncells, int D1, int D2, int cap) {
    __shared__ int sh[256];
    int t = threadIdx.x;
    int base = blockIdx.x * 1024 + t * 4;
    int v[4]; int s = 0;
    #pragma unroll
    for (int q = 0; q < 4; q++) { v[q] = (base + q < ncells) ? om[base + q] : 0; s += v[q]; }
    int incl = block_incl_scan(s, sh);
    int run = partials[blockIdx.x] + (incl - s);
    int D12 = D1 * D2;
    #pragma unroll
    for (int q = 0; q < 4; q++) {
        if (v[q]) {
            if (run < cap) {
                int lin = base + q;
                int i0 = lin / D12;
                int r2 = lin - i0 * D12;
                int i1 = r2 / D2;
                int i2 = r2 - i1 * D2;
                oc[run * 3] = i0; oc[run * 3 + 1] = i1; oc[run * 3 + 2] = i2;
            }
            run++;
        }
    }
}

__global__ __launch_bounds__(256) void k_lutscatter(const int* __restrict__ oc,
                                                    const int* __restrict__ pc,
                                                    int* __restrict__ lut, int D1, int D2) {
    int j = blockIdx.x * 256 + threadIdx.x;
    if (j >= *pc) return;
    lut[(oc[j * 3] * D1 + oc[j * 3 + 1]) * D2 + oc[j * 3 + 2]] = j;
}

__global__ __launch_bounds__(256) void k_mask2(const int* __restrict__ oc,
                                               const int* __restrict__ pc,
                                               int* __restrict__ om) {
    int j = blockIdx.x * 256 + threadIdx.x;
    if (j >= *pc) return;
    int p0 = oc[j * 3], p1 = oc[j * 3 + 1], p2 = oc[j * 3 + 2];
    int A[2], B[2], C[2]; int na, nb, nc;
    cand(p0, S2_0, A, na); cand(p1, S2_1, B, nb); cand(p2, S2_2, C, nc);
    for (int ia = 0; ia < na; ia++)
        for (int ib = 0; ib < nb; ib++)
            for (int ic = 0; ic < nc; ic++)
                om[(A[ia] * S2_1 + B[ib]) * S2_2 + C[ic]] = 1;
}

// ---------- weight pre-pack into MFMA B-fragment order ----------
__global__ __launch_bounds__(256) void k_prepack(const float* __restrict__ w,
        unsigned short* __restrict__ wp, int nk, int cin, int cout) {
    int tid = blockIdx.x * 256 + threadIdx.x;
    int tot = nk * cin * cout;
    if (tid >= tot) return;
    int co = tid % cout; int rest = tid / cout; int ci = rest % cin; int kk = rest / cin;
    int ks = ci >> 4, kr = ci & 15, half = kr >> 3, j = kr & 7;
    int nt = co >> 5, cl = co & 31, lane = half * 32 + cl;
    wp[((((size_t)kk * (cin >> 4) + ks) * (cout >> 5) + nt) * 64 + lane) * 8 + j] = f2b(w[tid]);
}

// ---------- MFMA gather-conv, register-staged pipeline ----------
// 128 gathered rows x COUT per block, 256 threads = 4 waves.
// COUT=128: wave w owns cols w*32..w*32+31 (TN=1) and ALL 128 rows (TM=4)
//   -> B fragments read once per block (no duplication), A from LDS.
// COUT=32:  wave w owns rows w*32..+31 (TM=1), all 32 cols.
// Pipeline: A-chunks for step k+1 loaded into REGISTERS (per-thread direct
// lut lookup, 2 steps ahead) while MFMAs of step k consume LDS; the vmcnt
// wait lands at the reg->LDS store after the MFMA block (no barrier drain
// of in-flight loads). SROW=CIN+8 keeps b128 LDS reads/writes bank-uniform.
// MODE 0: bn+relu  MODE 1: bn+res+relu  MODE 2: bias+gn16+relu -> fo_t[co][j]
template<int CIN, int COUT, int SD0, int SD1, int SD2, bool DOWN, int MODE>
__global__ __launch_bounds__(256)
void k_mconv(const unsigned short* __restrict__ fin, const int* __restrict__ lut,
             const int* __restrict__ oc, const int* __restrict__ pc,
             const unsigned short* __restrict__ wp,
             const float* __restrict__ p0, const float* __restrict__ p1,
             const float* __restrict__ p2,
             const unsigned short* __restrict__ res, void* __restrict__ fout_) {
    constexpr int KS = CIN / 16;
    constexpr int NT = COUT / 32;
    constexpr int SROW = CIN + 8;
    constexpr int CPR = CIN / 8;          // 16B chunks per row
    constexpr int HC  = CPR / 2;          // chunks staged per thread
    constexpr int TM  = (COUT == 128) ? 4 : 1;
    __shared__ unsigned short sA[128 * SROW];

    const int n = *pc;
    const int j0 = blockIdx.x * 128;
    if (j0 >= n) return;
    const int t = threadIdx.x;
    const int w = t >> 6, ln = t & 63, l31 = ln & 31, lh = ln >> 5;
    const int rowb = (COUT == 128) ? 0 : w * 32;
    const int colt = (COUT == 128) ? w : 0;

    // staging-row coords for this thread (row t>>1, half t&1)
    const int srow = t >> 1;
    int cxs, cys, czs;
    {
        int j = j0 + srow;
        if (j < n) { cxs = oc[j * 3]; cys = oc[j * 3 + 1]; czs = oc[j * 3 + 2]; }
        else       { cxs = -1000000; cys = -1000000; czs = -1000000; }
    }
    const uint4* fin4 = (const uint4*)fin;

    auto lookup = [&](int kk) -> int {
        int dx = kk / 9 - 1, dy = (kk / 3) % 3 - 1, dz = kk % 3 - 1;
        int x, y, z;
        if (DOWN) { x = 2 * cxs + dx; y = 2 * cys + dy; z = 2 * czs + dz; }
        else      { x = cxs + dx; y = cys + dy; z = czs + dz; }
        if ((unsigned)x < (unsigned)SD0 && (unsigned)y < (unsigned)SD1 && (unsigned)z < (unsigned)SD2)
            return lut[(x * SD1 + y) * SD2 + z];
        return -1;
    };

    uint4 ld[HC];
    auto loadrow = [&](int idx) {
        #pragma unroll
        for (int q = 0; q < HC; q++) {
            uint4 v = make_uint4(0, 0, 0, 0);
            if (idx >= 0) v = fin4[(size_t)idx * CPR + (t & 1) * HC + q];
            ld[q] = v;
        }
    };

    f32x16 acc[TM];
    #pragma unroll
    for (int a = 0; a < TM; a++)
        #pragma unroll
        for (int q = 0; q < 16; q++) acc[a][q] = 0.f;

    int idxA = lookup(0);
    loadrow(idxA);
    int idxB = lookup(1);

    for (int k = 0; k < 27; k++) {
        __syncthreads();   // prior step's sA reads complete
        #pragma unroll
        for (int q = 0; q < HC; q++)
            *(uint4*)&sA[srow * SROW + ((t & 1) * HC + q) * 8] = ld[q];
        __syncthreads();
        if (k < 26) {
            loadrow(idxB);                  // A data for k+1 (in flight over MFMAs)
            idxB = lookup(k + 2 <= 26 ? k + 2 : 26);   // lut for k+2
        }
        const unsigned short* wk = wp + (size_t)k * KS * NT * 512;
        #pragma unroll
        for (int ks = 0; ks < KS; ks++) {
            bf16x8 bfr = *(const bf16x8*)(wk + ((size_t)(ks * NT + colt) * 64 + ln) * 8);
            #pragma unroll
            for (int a = 0; a < TM; a++) {
                bf16x8 afr = *(const bf16x8*)(&sA[(rowb + a * 32 + l31) * SROW + ks * 16 + lh * 8]);
                acc[a] = __builtin_amdgcn_mfma_f32_32x32x16_bf16(afr, bfr, acc[a], 0, 0, 0);
            }
        }
    }

    const int co = colt * 32 + l31;
    if (MODE != 2) {
        unsigned short* fout = (unsigned short*)fout_;
        float g_ = p0[co], bb_ = p0[COUT + co], m_ = p0[2 * COUT + co];
        float iv = rsqrtf(p0[3 * COUT + co] + 1e-3f);
        #pragma unroll
        for (int a = 0; a < TM; a++) {
            #pragma unroll
            for (int r = 0; r < 16; r++) {
                int j = j0 + rowb + a * 32 + (r & 3) + 8 * (r >> 2) + 4 * lh;
                if (j < n) {
                    float y = (acc[a][r] - m_) * iv * g_ + bb_;
                    if (MODE == 1) y += b2f(res[(size_t)j * COUT + co]);
                    fout[(size_t)j * COUT + co] = f2b(fmaxf(y, 0.f));
                }
            }
        }
    } else {
        // MODE 2: bias + GN(16 groups of 8 ch) + relu -> fo_t[co*FOP + j]
        float* fo_t = (float*)fout_;
        float bias = p0[co], gg_ = p1[co], gb_ = p2[co];
        #pragma unroll
        for (int a = 0; a < TM; a++) {
            #pragma unroll
            for (int r = 0; r < 16; r++) {
                int j = j0 + a * 32 + (r & 3) + 8 * (r >> 2) + 4 * lh;
                float y = acc[a][r] + bias;
                float s = y;
                s += __shfl_xor(s, 1, 8);
                s += __shfl_xor(s, 2, 8);
                s += __shfl_xor(s, 4, 8);
                float m = s * 0.125f;
                float d = y - m;
                float q2 = d * d;
                q2 += __shfl_xor(q2, 1, 8);
                q2 += __shfl_xor(q2, 2, 8);
                q2 += __shfl_xor(q2, 4, 8);
                float var = q2 * 0.125f;
                float o = fmaxf(d * rsqrtf(var + 1e-5f) * gg_ + gb_, 0.f);
                fo_t[(size_t)co * FOP + j] = o;
            }
        }
    }
}

// ---------- dense output scatter (coalesced writes) ----------
// out[((co*128+cc)*88+bb)*14+aa]; one thread per element.
__global__ __launch_bounds__(256) void k_scatter(const float* __restrict__ fo_t,
                                                 const int* __restrict__ lut2,
                                                 float* __restrict__ dout) {
    int gid = blockIdx.x * 256 + threadIdx.x;
    int aa = gid % S2_0; int r = gid / S2_0;
    int bb = r % S2_1;   r /= S2_1;
    int cc = r % S2_2;   int co = r / S2_2;
    int idx = lut2[(aa * S2_1 + bb) * S2_2 + cc];
    float v = 0.f;
    if (idx >= 0) v = fo_t[(size_t)co * FOP + idx];
    dout[gid] = v;
}

// ---------- host ----------
extern "C" void kernel_launch(void* const* d_in, const int* in_sizes, int n_in,
                              void* d_out, int out_size, void* d_ws, size_t ws_size,
                              hipStream_t stream) {
    const float* vf    = (const float*)d_in[0];
    const int*   coors = (const int*)d_in[1];
    const float* et    = (const float*)d_in[3];
    const float* at    = (const float*)d_in[4];
    const float* wq    = (const float*)d_in[5];
    const float* bq    = (const float*)d_in[6];
    const float* wk_   = (const float*)d_in[7];
    const float* bk    = (const float*)d_in[8];
    const float* wv    = (const float*)d_in[9];
    const float* bv    = (const float*)d_in[10];
    const float* w_in  = (const float*)d_in[11];
    const float* b_in  = (const float*)d_in[12];
    const float* gin_g = (const float*)d_in[13];
    const float* gin_b = (const float*)d_in[14];
    const float* w_d1  = (const float*)d_in[15];
    const float* bn_d1 = (const float*)d_in[16];
    const float* w_r1  = (const float*)d_in[17];
    const float* bn_r1 = (const float*)d_in[18];
    const float* w_d2  = (const float*)d_in[19];
    const float* bn_d2 = (const float*)d_in[20];
    const float* w_r2  = (const float*)d_in[21];
    const float* bn_r2 = (const float*)d_in[22];
    const float* w_out = (const float*)d_in[23];
    const float* b_out = (const float*)d_in[24];
    const float* gout_g= (const float*)d_in[25];
    const float* gout_b= (const float*)d_in[26];

    char* ws = (char*)d_ws;
    size_t cur = 0;
    auto take = [&](size_t bytes) -> char* {
        char* p = ws + cur;
        cur += (bytes + 255) & ~(size_t)255;
        return p;
    };
    // Aliased region U (53.4 MB):
    //  phase 1: x_att @0, f0 bf16 @262144, lut0 @4194304 (40.1 MB)
    //  phase 2: fB1 bf16 @0 (22.4 MB)
    //  phase 3: fA2 @0 (17.7), fB2 @17694720 (17.7)
    //  phase 4: fo_t fp32 @17694720 (35.7 MB; fB2/lut0-tail dead)
    size_t usz1 = (size_t)4194304 + (size_t)CELLS0 * 4;
    size_t usz2 = (size_t)17694720 + (size_t)128 * FOP * 4;
    char* U = take(usz1 > usz2 ? usz1 : usz2);
    float*          x_att = (float*)U;
    unsigned short* f0    = (unsigned short*)(U + 262144);
    int*            lut0  = (int*)(U + 4194304);
    unsigned short* fB1   = (unsigned short*)U;
    unsigned short* fA2   = (unsigned short*)U;
    unsigned short* fB2   = (unsigned short*)(U + 17694720);
    float*          fo_t  = (float*)(U + 17694720);

    int*   om1      = (int*)take((size_t)CELLS1 * 4);
    int*   om2      = (int*)take((size_t)CELLS2 * 4);
    int*   partials = (int*)take(8192);
    int*   cnt      = (int*)take(256);
    int*   oc1      = (int*)take((size_t)CAP1 * 3 * 4);
    int*   oc2      = (int*)take((size_t)CAP2 * 3 * 4);
    unsigned short* fA1 = (unsigned short*)take((size_t)CAP1 * C1 * 2);
    int*   lut1     = (int*)take((size_t)CELLS1 * 4);
    int*   lut2     = (int*)take((size_t)CELLS2 * 4);
    unsigned short* wp_d1  = (unsigned short*)take((size_t)27 * 16 * 32 * 2);
    unsigned short* wp_r1  = (unsigned short*)take((size_t)108 * 32 * 32 * 2);
    unsigned short* wp_d2  = (unsigned short*)take((size_t)27 * 32 * 128 * 2);
    unsigned short* wp_r2  = (unsigned short*)take((size_t)108 * 128 * 128 * 2);
    unsigned short* wp_out = (unsigned short*)take((size_t)27 * 128 * 128 * 2);

    hipMemsetAsync(lut0, 0xFF, (size_t)CELLS0 * 4, stream);
    hipMemsetAsync(om1, 0, (size_t)CELLS1 * 4, stream);
    hipMemsetAsync(om2, 0, (size_t)CELLS2 * 4, stream);
    hipMemsetAsync(lut1, 0xFF, (size_t)CELLS1 * 4, stream);
    hipMemsetAsync(lut2, 0xFF, (size_t)CELLS2 * 4, stream);

    const int gN  = (NN + 255) / 256;
    const int gB1 = CELLS1 / 1024;
    const int gB2 = CELLS2 / 1024;
    const int gM1 = (CAP1 + 127) / 128;
    const int gM2 = (CAP2 + 127) / 128;
    const int gS1 = (CAP1 + 255) / 256;
    const int gS2 = (CAP2 + 255) / 256;

    k_prepack<<<(27*16*32   + 255)/256, 256, 0, stream>>>(w_d1,  wp_d1, 27, 16, 32);
    k_prepack<<<(108*32*32  + 255)/256, 256, 0, stream>>>(w_r1,  wp_r1, 108, 32, 32);
    k_prepack<<<(27*32*128  + 255)/256, 256, 0, stream>>>(w_d2,  wp_d2, 27, 32, 128);
    k_prepack<<<(108*128*128+ 255)/256, 256, 0, stream>>>(w_r2,  wp_r2, 108, 128, 128);
    k_prepack<<<(27*128*128 + 255)/256, 256, 0, stream>>>(w_out, wp_out, 27, 128, 128);

    k_init<<<gN, 256, 0, stream>>>(vf, coors, x_att, lut0, om1);
    k_attn<<<NRR, 256, 0, stream>>>(x_att, coors, et, at, wq, bq, wk_, bk, wv, bv);
    k_f0<<<gN, 256, 0, stream>>>(coors, x_att, w_in, b_in, gin_g, gin_b, f0);

    k_blocksum<<<gB1, 256, 0, stream>>>(om1, partials, CELLS1);
    k_scanparts<<<1, 256, 0, stream>>>(partials, gB1, cnt, CAP1);
    k_emit<<<gB1, 256, 0, stream>>>(om1, partials, oc1, CELLS1, S1_1, S1_2, CAP1);

    k_mconv<16, 32, S0_0, S0_1, S0_2, true, 0><<<gM1, 256, 0, stream>>>(
        f0, lut0, oc1, cnt, wp_d1, bn_d1, nullptr, nullptr, nullptr, fA1);
    k_lutscatter<<<gS1, 256, 0, stream>>>(oc1, cnt, lut1, S1_1, S1_2);

    k_mconv<32, 32, S1_0, S1_1, S1_2, false, 0><<<gM1, 256, 0, stream>>>(
        fA1, lut1, oc1, cnt, wp_r1 + 0 * 27648, bn_r1 + 0 * 128, nullptr, nullptr, nullptr, fB1);
    k_mconv<32, 32, S1_0, S1_1, S1_2, false, 1><<<gM1, 256, 0, stream>>>(
        fB1, lut1, oc1, cnt, wp_r1 + 1 * 27648, bn_r1 + 1 * 128, nullptr, nullptr, fA1, fA1);
    k_mconv<32, 32, S1_0, S1_1, S1_2, false, 0><<<gM1, 256, 0, stream>>>(
        fA1, lut1, oc1, cnt, wp_r1 + 2 * 27648, bn_r1 + 2 * 128, nullptr, nullptr, nullptr, fB1);
    k_mconv<32, 32, S1_0, S1_1, S1_2, false, 1><<<gM1, 256, 0, stream>>>(
        fB1, lut1, oc1, cnt, wp_r1 + 3 * 27648, bn_r1 + 3 * 128, nullptr, nullptr, fA1, fA1);

    k_mask2<<<gS1, 256, 0, stream>>>(oc1, cnt, om2);
    k_blocksum<<<gB2, 256, 0, stream>>>(om2, partials, CELLS2);
    k_scanparts<<<1, 256, 0, stream>>>(partials, gB2, cnt + 1, CAP2);
    k_emit<<<gB2, 256, 0, stream>>>(om2, partials, oc2, CELLS2, S2_1, S2_2, CAP2);

    k_mconv<32, 128, S1_0, S1_1, S1_2, true, 0><<<gM2, 256, 0, stream>>>(
        fA1, lut1, oc2, cnt + 1, wp_d2, bn_d2, nullptr, nullptr, nullptr, fA2);
    k_lutscatter<<<gS2, 256, 0, stream>>>(oc2, cnt + 1, lut2, S2_1, S2_2);

    const size_t wr2s = (size_t)27 * 128 * 128;
    k_mconv<128, 128, S2_0, S2_1, S2_2, false, 0><<<gM2, 256, 0, stream>>>(
        fA2, lut2, oc2, cnt + 1, wp_r2 + 0 * wr2s, bn_r2 + 0 * 512, nullptr, nullptr, nullptr, fB2);
    k_mconv<128, 128, S2_0, S2_1, S2_2, false, 1><<<gM2, 256, 0, stream>>>(
        fB2, lut2, oc2, cnt + 1, wp_r2 + 1 * wr2s, bn_r2 + 1 * 512, nullptr, nullptr, fA2, fA2);
    k_mconv<128, 128, S2_0, S2_1, S2_2, false, 0><<<gM2, 256, 0, stream>>>(
        fA2, lut2, oc2, cnt + 1, wp_r2 + 2 * wr2s, bn_r2 + 2 * 512, nullptr, nullptr, nullptr, fB2);
    k_mconv<128, 128, S2_0, S2_1, S2_2, false, 1><<<gM2, 256, 0, stream>>>(
        fB2, lut2, oc2, cnt + 1, wp_r2 + 3 * wr2s, bn_r2 + 3 * 512, nullptr, nullptr, fA2, fA2);

    // out conv -> fo_t (compact transposed), then coalesced dense scatter
    k_mconv<128, 128, S2_0, S2_1, S2_2, false, 2><<<gM2, 256, 0, stream>>>(
        fA2, lut2, oc2, cnt + 1, wp_out, b_out, gout_g, gout_b, nullptr, fo_t);
    k_scatter<<<(S2_0 * S2_1 * S2_2 * 128) / 256, 256, 0, stream>>>(fo_t, lut2, (float*)d_out);
}